// Round 10
// baseline (309.185 us; speedup 1.0000x reference)
//
#include <hip/hip_runtime.h>
#include <math.h>

#define N_NODES_C 50000
#define N_EDGES_C 200000
#define FDIM 128
#define NRBF 20
#define CUT 5.0f
#define SC_BLK 196   // ceil(50000/256)
#define GBLOCKS 4096
#define BATCH 32     // edges staged per LDS batch in gather

typedef short  bf16x8 __attribute__((ext_vector_type(8)));
typedef float  f32x4  __attribute__((ext_vector_type(4)));
typedef unsigned int u32x3 __attribute__((ext_vector_type(3)));

__device__ __forceinline__ unsigned short f32_to_bf16(float f) {
    unsigned u = __float_as_uint(f);
    unsigned r = (u + 0x7FFFu + ((u >> 16) & 1u)) >> 16;   // RNE
    return (unsigned short)r;
}
__device__ __forceinline__ float bf16_to_f32(unsigned short h) {
    return __uint_as_float(((unsigned)h) << 16);
}
__device__ __forceinline__ bf16x8 pack_bf16x8(float4 a, float4 b) {
    bf16x8 r;
    r[0] = (short)f32_to_bf16(a.x); r[1] = (short)f32_to_bf16(a.y);
    r[2] = (short)f32_to_bf16(a.z); r[3] = (short)f32_to_bf16(a.w);
    r[4] = (short)f32_to_bf16(b.x); r[5] = (short)f32_to_bf16(b.y);
    r[6] = (short)f32_to_bf16(b.z); r[7] = (short)f32_to_bf16(b.w);
    return r;
}

// ---------------------------------------------------------------------------
// Weight prep: W1t[n][k] = bf16(W1[k][n]) (128x128), W2t[n][k] = bf16(W2[k][n])
// ---------------------------------------------------------------------------
__global__ __launch_bounds__(256) void prep_w_kernel(
    const float* __restrict__ W1, const float* __restrict__ W2,
    unsigned short* __restrict__ W1t, unsigned short* __restrict__ W2t)
{
    int i = blockIdx.x * 256 + threadIdx.x;
    if (i < 128 * 128) {
        int n = i >> 7, k = i & 127;
        W1t[i] = f32_to_bf16(W1[k * 128 + n]);
    }
    int j = i - 128 * 128;
    if (j >= 0 && j < 384 * 128) {
        int n = j >> 7, k = j & 127;
        W2t[j] = f32_to_bf16(W2[k * 384 + n]);
    }
}

// ---------------------------------------------------------------------------
// Fused MLP + pack (MFMA): phi = silu(S@W1+b1)@W2+b2 computed per 64-node
// tile; phi tile staged in LDS (transposed [col][node]); epilogue packs
// pv[n][f] = {phi0,phi1,phi2, v0,v1,v2} bf16 (12B) with coalesced v reads.
// smem reused: first as h tile [64][136], then (after barrier) as
// phi_lds [384][66] (pad 66 -> stride 132B, bank-conflict-free col reads).
// ---------------------------------------------------------------------------
__global__ __launch_bounds__(256) void mlp12pack_kernel(
    const float* __restrict__ s, const unsigned short* __restrict__ W1t,
    const float* __restrict__ b1, const unsigned short* __restrict__ W2t,
    const float* __restrict__ b2, const float* __restrict__ v,
    unsigned short* __restrict__ pv)
{
    __shared__ unsigned short smem[384 * 66];   // 50.7 KB

    const int tid = threadIdx.x;
    const int wv = tid >> 6, lane = tid & 63;
    const int m0 = blockIdx.x * 64 + wv * 16;
    const int lr = lane & 15, lg = lane >> 4;
    int arow = m0 + lr; if (arow >= N_NODES_C) arow = N_NODES_C - 1;

#define HSM(r, c) smem[(r) * 136 + (c)]
#define PLD(col, n) smem[(col) * 66 + (n)]

    // ---- stage 1: h = silu(s @ W1 + b1) -> HSM ----
    {
        f32x4 acc[8];
#pragma unroll
        for (int nt = 0; nt < 8; ++nt) acc[nt] = (f32x4){0.f, 0.f, 0.f, 0.f};

#pragma unroll
        for (int kt = 0; kt < 4; ++kt) {
            const int k0 = kt * 32 + lg * 8;
            const float4* ap = (const float4*)(s + (size_t)arow * 128 + k0);
            bf16x8 af = pack_bf16x8(ap[0], ap[1]);
#pragma unroll
            for (int nt = 0; nt < 8; ++nt) {
                bf16x8 bf = *(const bf16x8*)(W1t + (size_t)(nt * 16 + lr) * 128 + k0);
                acc[nt] = __builtin_amdgcn_mfma_f32_16x16x32_bf16(af, bf, acc[nt], 0, 0, 0);
            }
        }

        const int lrow0 = wv * 16 + lg * 4;
#pragma unroll
        for (int nt = 0; nt < 8; ++nt) {
            int col = nt * 16 + lr;
            float bb = b1[col];
#pragma unroll
            for (int r = 0; r < 4; ++r) {
                float x = acc[nt][r] + bb;
                x = x / (1.f + __expf(-x));
                HSM(lrow0 + r, col) = f32_to_bf16(x);
            }
        }
    }
    __syncthreads();

    // A-frags for stage 2 from HSM
    bf16x8 af2[4];
#pragma unroll
    for (int kt = 0; kt < 4; ++kt)
        af2[kt] = *(const bf16x8*)&HSM(wv * 16 + lr, kt * 32 + lg * 8);
    __syncthreads();   // all HSM reads done before smem is reused as PLD

    // ---- stage 2: per 128-col chunk, mfma -> PLD (transposed) ----
    const int crow_l = wv * 16 + lg * 4;
#pragma unroll
    for (int c = 0; c < 3; ++c) {
        const int nbase = c * 128;
        f32x4 acc2[8];
#pragma unroll
        for (int nt = 0; nt < 8; ++nt) acc2[nt] = (f32x4){0.f, 0.f, 0.f, 0.f};

#pragma unroll
        for (int kt = 0; kt < 4; ++kt) {
            const int k0 = kt * 32 + lg * 8;
#pragma unroll
            for (int nt = 0; nt < 8; ++nt) {
                bf16x8 bf = *(const bf16x8*)(W2t + (size_t)(nbase + nt * 16 + lr) * 128 + k0);
                acc2[nt] = __builtin_amdgcn_mfma_f32_16x16x32_bf16(af2[kt], bf, acc2[nt], 0, 0, 0);
            }
        }

#pragma unroll
        for (int nt = 0; nt < 8; ++nt) {
            int col = nbase + nt * 16 + lr;
            float bb = b2[col];
#pragma unroll
            for (int r = 0; r < 4; ++r)
                PLD(col, crow_l + r) = f32_to_bf16(acc2[nt][r] + bb);
        }
    }
    __syncthreads();

    // ---- pack epilogue: pv[n][f] = {p0,p1,p2,v0,v1,v2} (12B) ----
    {
        const int f  = tid & 127;
        const int ns = tid >> 7;     // 0..1
#pragma unroll 4
        for (int i = 0; i < 32; ++i) {
            int ln = i * 2 + ns;
            int gn = blockIdx.x * 64 + ln;
            if (gn < N_NODES_C) {
                const float* vr = v + (size_t)gn * 384;
                unsigned short vb0 = f32_to_bf16(vr[f]);
                unsigned short vb1 = f32_to_bf16(vr[128 + f]);
                unsigned short vb2 = f32_to_bf16(vr[256 + f]);
                unsigned short p0 = PLD(f, ln), p1 = PLD(128 + f, ln), p2 = PLD(256 + f, ln);
                u32x3 val;
                val.x = (unsigned)p0 | ((unsigned)p1 << 16);
                val.y = (unsigned)p2 | ((unsigned)vb0 << 16);
                val.z = (unsigned)vb1 | ((unsigned)vb2 << 16);
                *(u32x3*)((char*)pv + (size_t)gn * 1536 + (size_t)f * 12) = val;
            }
        }
    }
#undef HSM
#undef PLD
}

// ---------------------------------------------------------------------------
// CSR build: histogram -> 3-kernel parallel scan -> fill
// ---------------------------------------------------------------------------
__global__ __launch_bounds__(256) void count_kernel(
    const int* __restrict__ dst, int* __restrict__ counts)
{
    int e = blockIdx.x * 256 + threadIdx.x;
    if (e < N_EDGES_C) atomicAdd(counts + dst[e], 1);
}

__global__ __launch_bounds__(256) void scan1_kernel(
    const int* __restrict__ counts, int* __restrict__ row_tmp,
    int* __restrict__ partial)
{
    __shared__ int sm[256];
    const int t = threadIdx.x;
    const int idx = blockIdx.x * 256 + t;
    int c = (idx < N_NODES_C) ? counts[idx] : 0;
    int x = c;
    sm[t] = x;
    __syncthreads();
#pragma unroll
    for (int off = 1; off < 256; off <<= 1) {
        int y = (t >= off) ? sm[t - off] : 0;
        __syncthreads();
        x += y;
        sm[t] = x;
        __syncthreads();
    }
    if (idx < N_NODES_C) row_tmp[idx] = x - c;
    if (t == 255) partial[blockIdx.x] = x;
}

__global__ __launch_bounds__(256) void scan2_kernel(
    const int* __restrict__ partial, int* __restrict__ poffs)
{
    __shared__ int sm[256];
    const int t = threadIdx.x;
    int c = (t < SC_BLK) ? partial[t] : 0;
    int x = c;
    sm[t] = x;
    __syncthreads();
#pragma unroll
    for (int off = 1; off < 256; off <<= 1) {
        int y = (t >= off) ? sm[t - off] : 0;
        __syncthreads();
        x += y;
        sm[t] = x;
        __syncthreads();
    }
    if (t < SC_BLK) poffs[t] = x - c;
}

__global__ __launch_bounds__(256) void scan3_kernel(
    const int* __restrict__ row_tmp, const int* __restrict__ poffs,
    int* __restrict__ row_ptr, int* __restrict__ row_fill)
{
    const int idx = blockIdx.x * 256 + threadIdx.x;
    if (idx < N_NODES_C) {
        int rp = row_tmp[idx] + poffs[blockIdx.x];
        row_ptr[idx]  = rp;
        row_fill[idx] = rp;
    }
    if (idx == 0) row_ptr[N_NODES_C] = N_EDGES_C;
}

// ---------------------------------------------------------------------------
// Edge precompute into dst-sorted slots; 128B (32-float) blob per edge:
//   [0..2]=dir, [3]=fcut, [4..23]=rbf[k]*invd*fcut, [24]=bitcast(src), rest pad
// ---------------------------------------------------------------------------
__global__ __launch_bounds__(256) void fill_kernel(
    const float* __restrict__ rel_pos, const int* __restrict__ src,
    const int* __restrict__ dst, int* __restrict__ row_fill,
    float* __restrict__ e_meta)
{
    int e = blockIdx.x * 256 + threadIdx.x;
    if (e >= N_EDGES_C) return;

    int pos = atomicAdd(row_fill + dst[e], 1);

    float x = rel_pos[3 * e + 0];
    float y = rel_pos[3 * e + 1];
    float z = rel_pos[3 * e + 2];
    float d = sqrtf(x * x + y * y + z * z);
    float invd = 1.0f / d;

    float s1 = 0.f, c1 = 0.f, fcut = 0.f, amp = 0.f;
    if (d < CUT) {
        sincosf((3.14159265358979f / CUT) * d, &s1, &c1);
        fcut = 0.5f * (c1 + 1.0f);
        amp  = invd * fcut;
    }

    float rb[NRBF];
    float sk = s1, ck = c1;
#pragma unroll
    for (int k = 0; k < NRBF; ++k) {
        rb[k] = sk * amp;
        float sn = sk * c1 + ck * s1;
        ck = ck * c1 - sk * s1;
        sk = sn;
    }

    float4* mp = (float4*)(e_meta + (size_t)pos * 32);
    mp[0] = make_float4(x * invd, y * invd, z * invd, fcut);
    mp[1] = make_float4(rb[0],  rb[1],  rb[2],  rb[3]);
    mp[2] = make_float4(rb[4],  rb[5],  rb[6],  rb[7]);
    mp[3] = make_float4(rb[8],  rb[9],  rb[10], rb[11]);
    mp[4] = make_float4(rb[12], rb[13], rb[14], rb[15]);
    mp[5] = make_float4(rb[16], rb[17], rb[18], rb[19]);
    mp[6] = make_float4(__int_as_float(src[e]), 0.f, 0.f, 0.f);
}

// ---------------------------------------------------------------------------
// Gather: per block (128 threads) a contiguous dst-sorted edge range; meta
// batch-staged via LDS (BATCH=32, double-buffered); pv gathers prefetched
// depth-3 (modulo-unrolled, no register rotation). One dwordx3 per edge/lane.
// __launch_bounds__(128,5): VGPR cap 102 so the 63 persistent Wr/br values
// stay in registers (round-9 lesson: default cap 64 -> compiler rematerialized
// Wr loads inside the edge loop). Round-5 lesson (don't cap below need) OK:
// structure needs ~95.
// ---------------------------------------------------------------------------
#define DOT_AND_ACC(MP, P0, P1, P2, V0, V1, V2)                                \
    {                                                                          \
        const float* mp_ = (MP);                                               \
        float4 m0 = *(const float4*)(mp_);                                     \
        float4 m1 = *(const float4*)(mp_ + 4);                                 \
        float4 m2 = *(const float4*)(mp_ + 8);                                 \
        float4 m3 = *(const float4*)(mp_ + 12);                                \
        float4 m4 = *(const float4*)(mp_ + 16);                                \
        float4 m5 = *(const float4*)(mp_ + 20);                                \
        float rr[NRBF] = {m1.x, m1.y, m1.z, m1.w, m2.x, m2.y, m2.z, m2.w,      \
                          m3.x, m3.y, m3.z, m3.w, m4.x, m4.y, m4.z, m4.w,      \
                          m5.x, m5.y, m5.z, m5.w};                             \
        float w0 = br0 * m0.w, w1 = br1 * m0.w, w2 = br2 * m0.w;               \
        _Pragma("unroll")                                                      \
        for (int k = 0; k < NRBF; ++k) {                                       \
            w0 += rr[k] * wr0[k];                                              \
            w1 += rr[k] * wr1[k];                                              \
            w2 += rr[k] * wr2[k];                                              \
        }                                                                      \
        float sv = w0 * (P0);                                                  \
        float ss = w1 * (P1);                                                  \
        float sr = w2 * (P2);                                                  \
        acc_s  += ss;                                                          \
        acc_v0 += (V0) * sv + m0.x * sr;                                       \
        acc_v1 += (V1) * sv + m0.y * sr;                                       \
        acc_v2 += (V2) * sv + m0.z * sr;                                       \
    }

#define COMPUTEPU(MP, U)                                                       \
    {                                                                          \
        float P0_ = bf16_to_f32((unsigned short)((U).x & 0xFFFFu));            \
        float P1_ = bf16_to_f32((unsigned short)((U).x >> 16));                \
        float P2_ = bf16_to_f32((unsigned short)((U).y & 0xFFFFu));            \
        float V0_ = bf16_to_f32((unsigned short)((U).y >> 16));                \
        float V1_ = bf16_to_f32((unsigned short)((U).z & 0xFFFFu));            \
        float V2_ = bf16_to_f32((unsigned short)((U).z >> 16));                \
        DOT_AND_ACC(MP, P0_, P1_, P2_, V0_, V1_, V2_)                          \
    }

#define LOADPV(U, SI)                                                          \
    U = *(const u32x3*)((const char*)pv + (size_t)(SI) * 1536 + (size_t)f * 12);

#define STORE_NODE(N_, AS, A0, A1, A2)                                         \
    {                                                                          \
        out_s[(size_t)(N_) * 128 + f] = AS;                                    \
        out_v[(size_t)(N_) * 384 +       f] = A0;                              \
        out_v[(size_t)(N_) * 384 + 128 + f] = A1;                              \
        out_v[(size_t)(N_) * 384 + 256 + f] = A2;                              \
    }

#define BOUNDARY(GE)                                                           \
    if ((GE) + 1 == end_cur) {                                                 \
        STORE_NODE(cur, acc_s, acc_v0, acc_v1, acc_v2);                        \
        acc_s = acc_v0 = acc_v1 = acc_v2 = 0.f;                                \
        ++cur;                                                                 \
        while (cur < nhi) {                                                    \
            int ne_ = row_ptr[cur + 1];                                        \
            if (ne_ != (GE) + 1) { end_cur = ne_; break; }                     \
            STORE_NODE(cur, 0.f, 0.f, 0.f, 0.f);                               \
            ++cur;                                                             \
        }                                                                      \
    }

#define PREFETCH(SLOT, TT)                                                     \
    if ((TT) < bcount) {                                                       \
        int si_ = __float_as_int(M[(TT) * 32 + 24]);                           \
        LOADPV(SLOT, si_);                                                     \
    }

__global__ __launch_bounds__(128, 5) void gather_packed_kernel(
    const unsigned short* __restrict__ pv, const float* __restrict__ Wr,
    const float* __restrict__ br, const int* __restrict__ row_ptr,
    const float* __restrict__ e_meta,
    float* __restrict__ out_v, float* __restrict__ out_s)
{
    __shared__ float meta_lds[2][BATCH * 32];

    const int f = threadIdx.x;               // 0..127 feature lane
    const int gid = blockIdx.x;
    const int chunk = (N_NODES_C + GBLOCKS - 1) / GBLOCKS;
    const int nlo = gid * chunk;
    if (nlo >= N_NODES_C) return;
    const int nhi = min(nlo + chunk, N_NODES_C);

    float wr0[NRBF], wr1[NRBF], wr2[NRBF];
#pragma unroll
    for (int k = 0; k < NRBF; ++k) {
        wr0[k] = Wr[k * 384 +       f];
        wr1[k] = Wr[k * 384 + 128 + f];
        wr2[k] = Wr[k * 384 + 256 + f];
    }
    const float br0 = br[f], br1 = br[128 + f], br2 = br[256 + f];

    const int gbeg = row_ptr[nlo];
    const int gend = row_ptr[nhi];
    const int nedge = gend - gbeg;

    float acc_s = 0.f, acc_v0 = 0.f, acc_v1 = 0.f, acc_v2 = 0.f;

    int cur = nlo;
    while (cur < nhi && row_ptr[cur + 1] == gbeg) {
        STORE_NODE(cur, 0.f, 0.f, 0.f, 0.f);
        ++cur;
    }
    int end_cur = (cur < nhi) ? row_ptr[cur + 1] : gbeg;

    // stage batch 0 (BATCH*32 floats = 256 float4 over 128 threads)
    if (nedge > 0) {
        const float4* src0 = (const float4*)(e_meta + (size_t)gbeg * 32);
        ((float4*)meta_lds[0])[threadIdx.x]       = src0[threadIdx.x];
        ((float4*)meta_lds[0])[threadIdx.x + 128] = src0[threadIdx.x + 128];
    }
    __syncthreads();

    const int total_batches = (nedge + BATCH - 1) / BATCH;
    for (int b = 0; b < total_batches; ++b) {
        const int bstart = b * BATCH;
        const int bcount = min(BATCH, nedge - bstart);
        const bool have_next = (b + 1 < total_batches);

        float4 st0, st1;
        if (have_next) {
            const float4* srcn =
                (const float4*)(e_meta + (size_t)(gbeg + bstart + BATCH) * 32);
            st0 = srcn[threadIdx.x];
            st1 = srcn[threadIdx.x + 128];
        }

        const float* M = meta_lds[b & 1];

        u32x3 u0, u1, u2;
        PREFETCH(u0, 0)
        PREFETCH(u1, 1)

        int t = 0;
        while (t < bcount) {
            PREFETCH(u2, t + 2)
            COMPUTEPU(M + t * 32, u0);
            BOUNDARY(gbeg + bstart + t);
            ++t; if (t >= bcount) break;

            PREFETCH(u0, t + 2)
            COMPUTEPU(M + t * 32, u1);
            BOUNDARY(gbeg + bstart + t);
            ++t; if (t >= bcount) break;

            PREFETCH(u1, t + 2)
            COMPUTEPU(M + t * 32, u2);
            BOUNDARY(gbeg + bstart + t);
            ++t;
        }

        if (have_next) {
            ((float4*)meta_lds[(b + 1) & 1])[threadIdx.x]       = st0;
            ((float4*)meta_lds[(b + 1) & 1])[threadIdx.x + 128] = st1;
        }
        __syncthreads();
    }
}

// ---------------------------------------------------------------------------
extern "C" void kernel_launch(void* const* d_in, const int* in_sizes, int n_in,
                              void* d_out, int out_size, void* d_ws, size_t ws_size,
                              hipStream_t stream)
{
    const float* s  = (const float*)d_in[0];
    const float* v  = (const float*)d_in[1];
    const float* rp = (const float*)d_in[2];
    const float* W1 = (const float*)d_in[3];
    const float* b1 = (const float*)d_in[4];
    const float* W2 = (const float*)d_in[5];
    const float* b2 = (const float*)d_in[6];
    const float* Wr = (const float*)d_in[7];
    const float* br = (const float*)d_in[8];
    const int* src  = (const int*)d_in[9];
    const int* dst  = (const int*)d_in[10];

    float* out   = (float*)d_out;
    float* out_v = out;                                    // 50000*3*128
    float* out_s = out + (size_t)N_NODES_C * 3 * FDIM;     // 50000*128

    // workspace layout (~103 MB total; no phi buffer anymore)
    char* ws = (char*)d_ws;
    float* e_meta = (float*)ws;                 ws += ((size_t)N_EDGES_C * 32 + 512) * sizeof(float);
    unsigned short* W1t = (unsigned short*)ws;  ws += (size_t)128 * 128 * sizeof(unsigned short);
    unsigned short* W2t = (unsigned short*)ws;  ws += (size_t)384 * 128 * sizeof(unsigned short);
    int* counts   = (int*)ws;                   ws += (size_t)N_NODES_C * sizeof(int);
    int* row_ptr  = (int*)ws;                   ws += (size_t)(N_NODES_C + 4) * sizeof(int);
    int* row_fill = (int*)ws;                   ws += (size_t)N_NODES_C * sizeof(int);
    int* row_tmp  = (int*)ws;                   ws += (size_t)N_NODES_C * sizeof(int);
    int* partial  = (int*)ws;                   ws += (size_t)256 * sizeof(int);
    int* poffs    = (int*)ws;                   ws += (size_t)256 * sizeof(int);
    unsigned short* pv = (unsigned short*)ws;   // 50000 * 768 ushorts = 76.8 MB

    hipMemsetAsync(counts, 0, (size_t)N_NODES_C * sizeof(int), stream);

    count_kernel<<<(N_EDGES_C + 255) / 256, 256, 0, stream>>>(dst, counts);
    scan1_kernel<<<SC_BLK, 256, 0, stream>>>(counts, row_tmp, partial);
    scan2_kernel<<<1, 256, 0, stream>>>(partial, poffs);
    scan3_kernel<<<SC_BLK, 256, 0, stream>>>(row_tmp, poffs, row_ptr, row_fill);
    fill_kernel<<<(N_EDGES_C + 255) / 256, 256, 0, stream>>>(rp, src, dst, row_fill, e_meta);

    prep_w_kernel<<<256, 256, 0, stream>>>(W1, W2, W1t, W2t);
    mlp12pack_kernel<<<(N_NODES_C + 63) / 64, 256, 0, stream>>>(s, W1t, b1, W2t, b2, v, pv);

    gather_packed_kernel<<<GBLOCKS, 128, 0, stream>>>(pv, Wr, br, row_ptr,
                                                      e_meta, out_v, out_s);
}

// Round 11
// 276.038 us; speedup vs baseline: 1.1201x; 1.1201x over previous
//
#include <hip/hip_runtime.h>
#include <math.h>

#define N_NODES_C 50000
#define N_EDGES_C 200000
#define FDIM 128
#define NRBF 20
#define CUT 5.0f
#define SC_BLK 196   // ceil(50000/256)
#define GBLOCKS 4096
#define BATCH 32     // edges staged per LDS batch in gather

typedef short  bf16x8 __attribute__((ext_vector_type(8)));
typedef float  f32x4  __attribute__((ext_vector_type(4)));
typedef unsigned int u32x3 __attribute__((ext_vector_type(3)));

__device__ __forceinline__ unsigned short f32_to_bf16(float f) {
    unsigned u = __float_as_uint(f);
    unsigned r = (u + 0x7FFFu + ((u >> 16) & 1u)) >> 16;   // RNE
    return (unsigned short)r;
}
__device__ __forceinline__ float bf16_to_f32(unsigned short h) {
    return __uint_as_float(((unsigned)h) << 16);
}
__device__ __forceinline__ bf16x8 pack_bf16x8(float4 a, float4 b) {
    bf16x8 r;
    r[0] = (short)f32_to_bf16(a.x); r[1] = (short)f32_to_bf16(a.y);
    r[2] = (short)f32_to_bf16(a.z); r[3] = (short)f32_to_bf16(a.w);
    r[4] = (short)f32_to_bf16(b.x); r[5] = (short)f32_to_bf16(b.y);
    r[6] = (short)f32_to_bf16(b.z); r[7] = (short)f32_to_bf16(b.w);
    return r;
}

// ---------------------------------------------------------------------------
// Weight prep: W1t[n][k] = bf16(W1[k][n]) (128x128), W2t[n][k] = bf16(W2[k][n])
// ---------------------------------------------------------------------------
__global__ __launch_bounds__(256) void prep_w_kernel(
    const float* __restrict__ W1, const float* __restrict__ W2,
    unsigned short* __restrict__ W1t, unsigned short* __restrict__ W2t)
{
    int i = blockIdx.x * 256 + threadIdx.x;
    if (i < 128 * 128) {
        int n = i >> 7, k = i & 127;
        W1t[i] = f32_to_bf16(W1[k * 128 + n]);
    }
    int j = i - 128 * 128;
    if (j >= 0 && j < 384 * 128) {
        int n = j >> 7, k = j & 127;
        W2t[j] = f32_to_bf16(W2[k * 384 + n]);
    }
}

// ---------------------------------------------------------------------------
// Fused MLP -> pv (MFMA): stage1 h=silu(S@W1+b1) via LDS (17.4 KB only);
// stage2 with nt OUTER and the three 128-col chunks computed TOGETHER, so
// each thread's (lane,reg) slot holds the {phi0,phi1,phi2} triple for its
// output element and writes the 12B pv record directly — no phi buffer, no
// LDS transpose (round-10 lesson: 50.7KB LDS + transpose = 150us disaster).
// ---------------------------------------------------------------------------
__global__ __launch_bounds__(256) void mlp12pv_kernel(
    const float* __restrict__ s, const unsigned short* __restrict__ W1t,
    const float* __restrict__ b1, const unsigned short* __restrict__ W2t,
    const float* __restrict__ b2, const float* __restrict__ v,
    unsigned short* __restrict__ pv)
{
    __shared__ unsigned short hsm[64][136];   // 17.4 KB, pad 136 vs conflicts

    const int tid = threadIdx.x;
    const int wv = tid >> 6, lane = tid & 63;
    const int m0 = blockIdx.x * 64 + wv * 16;
    const int lr = lane & 15, lg = lane >> 4;
    int arow = m0 + lr; if (arow >= N_NODES_C) arow = N_NODES_C - 1;

    // ---- stage 1: h = silu(s @ W1 + b1) -> hsm ----
    {
        f32x4 acc[8];
#pragma unroll
        for (int nt = 0; nt < 8; ++nt) acc[nt] = (f32x4){0.f, 0.f, 0.f, 0.f};

#pragma unroll
        for (int kt = 0; kt < 4; ++kt) {
            const int k0 = kt * 32 + lg * 8;
            const float4* ap = (const float4*)(s + (size_t)arow * 128 + k0);
            bf16x8 af = pack_bf16x8(ap[0], ap[1]);
#pragma unroll
            for (int nt = 0; nt < 8; ++nt) {
                bf16x8 bf = *(const bf16x8*)(W1t + (size_t)(nt * 16 + lr) * 128 + k0);
                acc[nt] = __builtin_amdgcn_mfma_f32_16x16x32_bf16(af, bf, acc[nt], 0, 0, 0);
            }
        }

        const int lrow0 = wv * 16 + lg * 4;
#pragma unroll
        for (int nt = 0; nt < 8; ++nt) {
            int col = nt * 16 + lr;
            float bb = b1[col];
#pragma unroll
            for (int r = 0; r < 4; ++r) {
                float x = acc[nt][r] + bb;
                x = x / (1.f + __expf(-x));
                hsm[lrow0 + r][col] = f32_to_bf16(x);
            }
        }
    }
    __syncthreads();

    // A-frags for stage 2 from hsm
    bf16x8 af2[4];
#pragma unroll
    for (int kt = 0; kt < 4; ++kt)
        af2[kt] = *(const bf16x8*)&hsm[wv * 16 + lr][kt * 32 + lg * 8];

    // ---- stage 2: nt outer, 3 chunks together, direct pv write ----
    const int crow = m0 + lg * 4;
#pragma unroll
    for (int nt = 0; nt < 8; ++nt) {
        f32x4 a0 = (f32x4){0.f, 0.f, 0.f, 0.f};
        f32x4 a1 = (f32x4){0.f, 0.f, 0.f, 0.f};
        f32x4 a2 = (f32x4){0.f, 0.f, 0.f, 0.f};
#pragma unroll
        for (int kt = 0; kt < 4; ++kt) {
            const int k0 = kt * 32 + lg * 8;
            const size_t wrow = (size_t)(nt * 16 + lr) * 128 + k0;
            bf16x8 bf0 = *(const bf16x8*)(W2t + wrow);
            bf16x8 bf1 = *(const bf16x8*)(W2t + (size_t)128 * 128 + wrow);
            bf16x8 bf2 = *(const bf16x8*)(W2t + (size_t)256 * 128 + wrow);
            a0 = __builtin_amdgcn_mfma_f32_16x16x32_bf16(af2[kt], bf0, a0, 0, 0, 0);
            a1 = __builtin_amdgcn_mfma_f32_16x16x32_bf16(af2[kt], bf1, a1, 0, 0, 0);
            a2 = __builtin_amdgcn_mfma_f32_16x16x32_bf16(af2[kt], bf2, a2, 0, 0, 0);
        }

        const int col = nt * 16 + lr;
        const float bb0 = b2[col], bb1 = b2[128 + col], bb2 = b2[256 + col];
#pragma unroll
        for (int r = 0; r < 4; ++r) {
            int m = crow + r;
            if (m < N_NODES_C) {
                const float* vr = v + (size_t)m * 384;
                unsigned short p0 = f32_to_bf16(a0[r] + bb0);
                unsigned short p1 = f32_to_bf16(a1[r] + bb1);
                unsigned short p2 = f32_to_bf16(a2[r] + bb2);
                unsigned short v0 = f32_to_bf16(vr[col]);
                unsigned short v1 = f32_to_bf16(vr[128 + col]);
                unsigned short v2 = f32_to_bf16(vr[256 + col]);
                u32x3 val;
                val.x = (unsigned)p0 | ((unsigned)p1 << 16);
                val.y = (unsigned)p2 | ((unsigned)v0 << 16);
                val.z = (unsigned)v1 | ((unsigned)v2 << 16);
                *(u32x3*)((char*)pv + (size_t)m * 1536 + (size_t)col * 12) = val;
            }
        }
    }
}

// ---------------------------------------------------------------------------
// CSR build: histogram -> 3-kernel parallel scan -> fill
// ---------------------------------------------------------------------------
__global__ __launch_bounds__(256) void count_kernel(
    const int* __restrict__ dst, int* __restrict__ counts)
{
    int e = blockIdx.x * 256 + threadIdx.x;
    if (e < N_EDGES_C) atomicAdd(counts + dst[e], 1);
}

__global__ __launch_bounds__(256) void scan1_kernel(
    const int* __restrict__ counts, int* __restrict__ row_tmp,
    int* __restrict__ partial)
{
    __shared__ int sm[256];
    const int t = threadIdx.x;
    const int idx = blockIdx.x * 256 + t;
    int c = (idx < N_NODES_C) ? counts[idx] : 0;
    int x = c;
    sm[t] = x;
    __syncthreads();
#pragma unroll
    for (int off = 1; off < 256; off <<= 1) {
        int y = (t >= off) ? sm[t - off] : 0;
        __syncthreads();
        x += y;
        sm[t] = x;
        __syncthreads();
    }
    if (idx < N_NODES_C) row_tmp[idx] = x - c;
    if (t == 255) partial[blockIdx.x] = x;
}

__global__ __launch_bounds__(256) void scan2_kernel(
    const int* __restrict__ partial, int* __restrict__ poffs)
{
    __shared__ int sm[256];
    const int t = threadIdx.x;
    int c = (t < SC_BLK) ? partial[t] : 0;
    int x = c;
    sm[t] = x;
    __syncthreads();
#pragma unroll
    for (int off = 1; off < 256; off <<= 1) {
        int y = (t >= off) ? sm[t - off] : 0;
        __syncthreads();
        x += y;
        sm[t] = x;
        __syncthreads();
    }
    if (t < SC_BLK) poffs[t] = x - c;
}

__global__ __launch_bounds__(256) void scan3_kernel(
    const int* __restrict__ row_tmp, const int* __restrict__ poffs,
    int* __restrict__ row_ptr, int* __restrict__ row_fill)
{
    const int idx = blockIdx.x * 256 + threadIdx.x;
    if (idx < N_NODES_C) {
        int rp = row_tmp[idx] + poffs[blockIdx.x];
        row_ptr[idx]  = rp;
        row_fill[idx] = rp;
    }
    if (idx == 0) row_ptr[N_NODES_C] = N_EDGES_C;
}

// ---------------------------------------------------------------------------
// Edge precompute into dst-sorted slots; 128B (32-float) blob per edge:
//   [0..2]=dir, [3]=fcut, [4..23]=rbf[k]*invd*fcut, [24]=bitcast(src), rest pad
// ---------------------------------------------------------------------------
__global__ __launch_bounds__(256) void fill_kernel(
    const float* __restrict__ rel_pos, const int* __restrict__ src,
    const int* __restrict__ dst, int* __restrict__ row_fill,
    float* __restrict__ e_meta)
{
    int e = blockIdx.x * 256 + threadIdx.x;
    if (e >= N_EDGES_C) return;

    int pos = atomicAdd(row_fill + dst[e], 1);

    float x = rel_pos[3 * e + 0];
    float y = rel_pos[3 * e + 1];
    float z = rel_pos[3 * e + 2];
    float d = sqrtf(x * x + y * y + z * z);
    float invd = 1.0f / d;

    float s1 = 0.f, c1 = 0.f, fcut = 0.f, amp = 0.f;
    if (d < CUT) {
        sincosf((3.14159265358979f / CUT) * d, &s1, &c1);
        fcut = 0.5f * (c1 + 1.0f);
        amp  = invd * fcut;
    }

    float rb[NRBF];
    float sk = s1, ck = c1;
#pragma unroll
    for (int k = 0; k < NRBF; ++k) {
        rb[k] = sk * amp;
        float sn = sk * c1 + ck * s1;
        ck = ck * c1 - sk * s1;
        sk = sn;
    }

    float4* mp = (float4*)(e_meta + (size_t)pos * 32);
    mp[0] = make_float4(x * invd, y * invd, z * invd, fcut);
    mp[1] = make_float4(rb[0],  rb[1],  rb[2],  rb[3]);
    mp[2] = make_float4(rb[4],  rb[5],  rb[6],  rb[7]);
    mp[3] = make_float4(rb[8],  rb[9],  rb[10], rb[11]);
    mp[4] = make_float4(rb[12], rb[13], rb[14], rb[15]);
    mp[5] = make_float4(rb[16], rb[17], rb[18], rb[19]);
    mp[6] = make_float4(__int_as_float(src[e]), 0.f, 0.f, 0.f);
}

// ---------------------------------------------------------------------------
// Gather: per block (128 threads) a contiguous dst-sorted edge range; meta
// batch-staged via LDS (BATCH=32, double-buffered); pv gathers prefetched
// depth-3 (modulo-unrolled). One dwordx3 per edge per lane.
// __launch_bounds__(128,5): VGPR cap 102 so the 63 persistent Wr/br values
// stay in registers (round-9 lesson: default cap 64 -> remat inside loop).
// ---------------------------------------------------------------------------
#define DOT_AND_ACC(MP, P0, P1, P2, V0, V1, V2)                                \
    {                                                                          \
        const float* mp_ = (MP);                                               \
        float4 m0 = *(const float4*)(mp_);                                     \
        float4 m1 = *(const float4*)(mp_ + 4);                                 \
        float4 m2 = *(const float4*)(mp_ + 8);                                 \
        float4 m3 = *(const float4*)(mp_ + 12);                                \
        float4 m4 = *(const float4*)(mp_ + 16);                                \
        float4 m5 = *(const float4*)(mp_ + 20);                                \
        float rr[NRBF] = {m1.x, m1.y, m1.z, m1.w, m2.x, m2.y, m2.z, m2.w,      \
                          m3.x, m3.y, m3.z, m3.w, m4.x, m4.y, m4.z, m4.w,      \
                          m5.x, m5.y, m5.z, m5.w};                             \
        float w0 = br0 * m0.w, w1 = br1 * m0.w, w2 = br2 * m0.w;               \
        _Pragma("unroll")                                                      \
        for (int k = 0; k < NRBF; ++k) {                                       \
            w0 += rr[k] * wr0[k];                                              \
            w1 += rr[k] * wr1[k];                                              \
            w2 += rr[k] * wr2[k];                                              \
        }                                                                      \
        float sv = w0 * (P0);                                                  \
        float ss = w1 * (P1);                                                  \
        float sr = w2 * (P2);                                                  \
        acc_s  += ss;                                                          \
        acc_v0 += (V0) * sv + m0.x * sr;                                       \
        acc_v1 += (V1) * sv + m0.y * sr;                                       \
        acc_v2 += (V2) * sv + m0.z * sr;                                       \
    }

#define COMPUTEPU(MP, U)                                                       \
    {                                                                          \
        float P0_ = bf16_to_f32((unsigned short)((U).x & 0xFFFFu));            \
        float P1_ = bf16_to_f32((unsigned short)((U).x >> 16));                \
        float P2_ = bf16_to_f32((unsigned short)((U).y & 0xFFFFu));            \
        float V0_ = bf16_to_f32((unsigned short)((U).y >> 16));                \
        float V1_ = bf16_to_f32((unsigned short)((U).z & 0xFFFFu));            \
        float V2_ = bf16_to_f32((unsigned short)((U).z >> 16));                \
        DOT_AND_ACC(MP, P0_, P1_, P2_, V0_, V1_, V2_)                          \
    }

#define LOADPV(U, SI)                                                          \
    U = *(const u32x3*)((const char*)pv + (size_t)(SI) * 1536 + (size_t)f * 12);

#define STORE_NODE(N_, AS, A0, A1, A2)                                         \
    {                                                                          \
        out_s[(size_t)(N_) * 128 + f] = AS;                                    \
        out_v[(size_t)(N_) * 384 +       f] = A0;                              \
        out_v[(size_t)(N_) * 384 + 128 + f] = A1;                              \
        out_v[(size_t)(N_) * 384 + 256 + f] = A2;                              \
    }

#define BOUNDARY(GE)                                                           \
    if ((GE) + 1 == end_cur) {                                                 \
        STORE_NODE(cur, acc_s, acc_v0, acc_v1, acc_v2);                        \
        acc_s = acc_v0 = acc_v1 = acc_v2 = 0.f;                                \
        ++cur;                                                                 \
        while (cur < nhi) {                                                    \
            int ne_ = row_ptr[cur + 1];                                        \
            if (ne_ != (GE) + 1) { end_cur = ne_; break; }                     \
            STORE_NODE(cur, 0.f, 0.f, 0.f, 0.f);                               \
            ++cur;                                                             \
        }                                                                      \
    }

#define PREFETCH(SLOT, TT)                                                     \
    if ((TT) < bcount) {                                                       \
        int si_ = __float_as_int(M[(TT) * 32 + 24]);                           \
        LOADPV(SLOT, si_);                                                     \
    }

__global__ __launch_bounds__(128, 5) void gather_packed_kernel(
    const unsigned short* __restrict__ pv, const float* __restrict__ Wr,
    const float* __restrict__ br, const int* __restrict__ row_ptr,
    const float* __restrict__ e_meta,
    float* __restrict__ out_v, float* __restrict__ out_s)
{
    __shared__ float meta_lds[2][BATCH * 32];

    const int f = threadIdx.x;               // 0..127 feature lane
    const int gid = blockIdx.x;
    const int chunk = (N_NODES_C + GBLOCKS - 1) / GBLOCKS;
    const int nlo = gid * chunk;
    if (nlo >= N_NODES_C) return;
    const int nhi = min(nlo + chunk, N_NODES_C);

    float wr0[NRBF], wr1[NRBF], wr2[NRBF];
#pragma unroll
    for (int k = 0; k < NRBF; ++k) {
        wr0[k] = Wr[k * 384 +       f];
        wr1[k] = Wr[k * 384 + 128 + f];
        wr2[k] = Wr[k * 384 + 256 + f];
    }
    const float br0 = br[f], br1 = br[128 + f], br2 = br[256 + f];

    const int gbeg = row_ptr[nlo];
    const int gend = row_ptr[nhi];
    const int nedge = gend - gbeg;

    float acc_s = 0.f, acc_v0 = 0.f, acc_v1 = 0.f, acc_v2 = 0.f;

    int cur = nlo;
    while (cur < nhi && row_ptr[cur + 1] == gbeg) {
        STORE_NODE(cur, 0.f, 0.f, 0.f, 0.f);
        ++cur;
    }
    int end_cur = (cur < nhi) ? row_ptr[cur + 1] : gbeg;

    // stage batch 0 (BATCH*32 floats = 256 float4 over 128 threads)
    if (nedge > 0) {
        const float4* src0 = (const float4*)(e_meta + (size_t)gbeg * 32);
        ((float4*)meta_lds[0])[threadIdx.x]       = src0[threadIdx.x];
        ((float4*)meta_lds[0])[threadIdx.x + 128] = src0[threadIdx.x + 128];
    }
    __syncthreads();

    const int total_batches = (nedge + BATCH - 1) / BATCH;
    for (int b = 0; b < total_batches; ++b) {
        const int bstart = b * BATCH;
        const int bcount = min(BATCH, nedge - bstart);
        const bool have_next = (b + 1 < total_batches);

        float4 st0, st1;
        if (have_next) {
            const float4* srcn =
                (const float4*)(e_meta + (size_t)(gbeg + bstart + BATCH) * 32);
            st0 = srcn[threadIdx.x];
            st1 = srcn[threadIdx.x + 128];
        }

        const float* M = meta_lds[b & 1];

        u32x3 u0, u1, u2;
        PREFETCH(u0, 0)
        PREFETCH(u1, 1)

        int t = 0;
        while (t < bcount) {
            PREFETCH(u2, t + 2)
            COMPUTEPU(M + t * 32, u0);
            BOUNDARY(gbeg + bstart + t);
            ++t; if (t >= bcount) break;

            PREFETCH(u0, t + 2)
            COMPUTEPU(M + t * 32, u1);
            BOUNDARY(gbeg + bstart + t);
            ++t; if (t >= bcount) break;

            PREFETCH(u1, t + 2)
            COMPUTEPU(M + t * 32, u2);
            BOUNDARY(gbeg + bstart + t);
            ++t;
        }

        if (have_next) {
            ((float4*)meta_lds[(b + 1) & 1])[threadIdx.x]       = st0;
            ((float4*)meta_lds[(b + 1) & 1])[threadIdx.x + 128] = st1;
        }
        __syncthreads();
    }
}

// ---------------------------------------------------------------------------
extern "C" void kernel_launch(void* const* d_in, const int* in_sizes, int n_in,
                              void* d_out, int out_size, void* d_ws, size_t ws_size,
                              hipStream_t stream)
{
    const float* s  = (const float*)d_in[0];
    const float* v  = (const float*)d_in[1];
    const float* rp = (const float*)d_in[2];
    const float* W1 = (const float*)d_in[3];
    const float* b1 = (const float*)d_in[4];
    const float* W2 = (const float*)d_in[5];
    const float* b2 = (const float*)d_in[6];
    const float* Wr = (const float*)d_in[7];
    const float* br = (const float*)d_in[8];
    const int* src  = (const int*)d_in[9];
    const int* dst  = (const int*)d_in[10];

    float* out   = (float*)d_out;
    float* out_v = out;                                    // 50000*3*128
    float* out_s = out + (size_t)N_NODES_C * 3 * FDIM;     // 50000*128

    // workspace layout (~103 MB total; no phi buffer)
    char* ws = (char*)d_ws;
    float* e_meta = (float*)ws;                 ws += ((size_t)N_EDGES_C * 32 + 512) * sizeof(float);
    unsigned short* W1t = (unsigned short*)ws;  ws += (size_t)128 * 128 * sizeof(unsigned short);
    unsigned short* W2t = (unsigned short*)ws;  ws += (size_t)384 * 128 * sizeof(unsigned short);
    int* counts   = (int*)ws;                   ws += (size_t)N_NODES_C * sizeof(int);
    int* row_ptr  = (int*)ws;                   ws += (size_t)(N_NODES_C + 4) * sizeof(int);
    int* row_fill = (int*)ws;                   ws += (size_t)N_NODES_C * sizeof(int);
    int* row_tmp  = (int*)ws;                   ws += (size_t)N_NODES_C * sizeof(int);
    int* partial  = (int*)ws;                   ws += (size_t)256 * sizeof(int);
    int* poffs    = (int*)ws;                   ws += (size_t)256 * sizeof(int);
    unsigned short* pv = (unsigned short*)ws;   // 50000 * 768 ushorts = 76.8 MB

    hipMemsetAsync(counts, 0, (size_t)N_NODES_C * sizeof(int), stream);

    count_kernel<<<(N_EDGES_C + 255) / 256, 256, 0, stream>>>(dst, counts);
    scan1_kernel<<<SC_BLK, 256, 0, stream>>>(counts, row_tmp, partial);
    scan2_kernel<<<1, 256, 0, stream>>>(partial, poffs);
    scan3_kernel<<<SC_BLK, 256, 0, stream>>>(row_tmp, poffs, row_ptr, row_fill);
    fill_kernel<<<(N_EDGES_C + 255) / 256, 256, 0, stream>>>(rp, src, dst, row_fill, e_meta);

    prep_w_kernel<<<256, 256, 0, stream>>>(W1, W2, W1t, W2t);
    mlp12pv_kernel<<<(N_NODES_C + 63) / 64, 256, 0, stream>>>(s, W1t, b1, W2t, b2, v, pv);

    gather_packed_kernel<<<GBLOCKS, 128, 0, stream>>>(pv, Wr, br, row_ptr,
                                                      e_meta, out_v, out_s);
}

// Round 12
// 250.690 us; speedup vs baseline: 1.2333x; 1.1011x over previous
//
#include <hip/hip_runtime.h>
#include <math.h>

#define N_NODES_C 50000
#define N_EDGES_C 200000
#define FDIM 128
#define NRBF 20
#define CUT 5.0f
#define SC_BLK 196   // ceil(50000/256)
#define GBLOCKS 4096
#define BATCH 32     // edges staged per LDS batch (32 x 64B = 2KB = 128 float4)

typedef short  bf16x8 __attribute__((ext_vector_type(8)));
typedef float  f32x4  __attribute__((ext_vector_type(4)));
typedef _Float16 f16x2 __attribute__((ext_vector_type(2)));

__device__ __forceinline__ unsigned short f32_to_bf16(float f) {
    unsigned u = __float_as_uint(f);
    unsigned r = (u + 0x7FFFu + ((u >> 16) & 1u)) >> 16;   // RNE
    return (unsigned short)r;
}
__device__ __forceinline__ float bf16_to_f32(unsigned short h) {
    return __uint_as_float(((unsigned)h) << 16);
}
__device__ __forceinline__ unsigned short f16_bits(float x) {
    _Float16 h = (_Float16)x;
    unsigned short b;
    __builtin_memcpy(&b, &h, 2);
    return b;
}
__device__ __forceinline__ f16x2 u2h2(unsigned u) {
    f16x2 r;
    __builtin_memcpy(&r, &u, 4);
    return r;
}
__device__ __forceinline__ bf16x8 pack_bf16x8(float4 a, float4 b) {
    bf16x8 r;
    r[0] = (short)f32_to_bf16(a.x); r[1] = (short)f32_to_bf16(a.y);
    r[2] = (short)f32_to_bf16(a.z); r[3] = (short)f32_to_bf16(a.w);
    r[4] = (short)f32_to_bf16(b.x); r[5] = (short)f32_to_bf16(b.y);
    r[6] = (short)f32_to_bf16(b.z); r[7] = (short)f32_to_bf16(b.w);
    return r;
}

// ---------------------------------------------------------------------------
// Weight prep: W1t[n][k] = bf16(W1[k][n]) (128x128), W2t[n][k] = bf16(W2[k][n])
// ---------------------------------------------------------------------------
__global__ __launch_bounds__(256) void prep_w_kernel(
    const float* __restrict__ W1, const float* __restrict__ W2,
    unsigned short* __restrict__ W1t, unsigned short* __restrict__ W2t)
{
    int i = blockIdx.x * 256 + threadIdx.x;
    if (i < 128 * 128) {
        int n = i >> 7, k = i & 127;
        W1t[i] = f32_to_bf16(W1[k * 128 + n]);
    }
    int j = i - 128 * 128;
    if (j >= 0 && j < 384 * 128) {
        int n = j >> 7, k = j & 127;
        W2t[j] = f32_to_bf16(W2[k * 384 + n]);
    }
}

// ---------------------------------------------------------------------------
// Wr prep: per-lane packed f16 pairs.
// wrh[f*30 + sec*10 + kp] = half2{ Wr[2kp][sec*128+f], Wr[2kp+1][sec*128+f] }
// ---------------------------------------------------------------------------
__global__ __launch_bounds__(256) void prep_wr_kernel(
    const float* __restrict__ Wr, unsigned* __restrict__ wrh)
{
    int idx = blockIdx.x * 256 + threadIdx.x;
    if (idx >= 128 * 30) return;
    int f  = idx / 30;
    int r  = idx % 30;
    int sec = r / 10, kp = r % 10;
    int col = sec * 128 + f;
    unsigned lo = f16_bits(Wr[(2 * kp)     * 384 + col]);
    unsigned hi = f16_bits(Wr[(2 * kp + 1) * 384 + col]);
    wrh[idx] = lo | (hi << 16);
}

// ---------------------------------------------------------------------------
// Fused MLP -> pv (MFMA): stage1 h=silu(S@W1+b1) via LDS (17.4 KB);
// stage2 nt-outer, 3 col-chunks together -> each thread holds {phi0,phi1,phi2}
// triple in-register, packs pv record (16B aligned) directly.
// ---------------------------------------------------------------------------
__global__ __launch_bounds__(256) void mlp12pv_kernel(
    const float* __restrict__ s, const unsigned short* __restrict__ W1t,
    const float* __restrict__ b1, const unsigned short* __restrict__ W2t,
    const float* __restrict__ b2, const float* __restrict__ v,
    unsigned short* __restrict__ pv)
{
    __shared__ unsigned short hsm[64][136];   // 17.4 KB

    const int tid = threadIdx.x;
    const int wv = tid >> 6, lane = tid & 63;
    const int m0 = blockIdx.x * 64 + wv * 16;
    const int lr = lane & 15, lg = lane >> 4;
    int arow = m0 + lr; if (arow >= N_NODES_C) arow = N_NODES_C - 1;

    // ---- stage 1 ----
    {
        f32x4 acc[8];
#pragma unroll
        for (int nt = 0; nt < 8; ++nt) acc[nt] = (f32x4){0.f, 0.f, 0.f, 0.f};

#pragma unroll
        for (int kt = 0; kt < 4; ++kt) {
            const int k0 = kt * 32 + lg * 8;
            const float4* ap = (const float4*)(s + (size_t)arow * 128 + k0);
            bf16x8 af = pack_bf16x8(ap[0], ap[1]);
#pragma unroll
            for (int nt = 0; nt < 8; ++nt) {
                bf16x8 bf = *(const bf16x8*)(W1t + (size_t)(nt * 16 + lr) * 128 + k0);
                acc[nt] = __builtin_amdgcn_mfma_f32_16x16x32_bf16(af, bf, acc[nt], 0, 0, 0);
            }
        }

        const int lrow0 = wv * 16 + lg * 4;
#pragma unroll
        for (int nt = 0; nt < 8; ++nt) {
            int col = nt * 16 + lr;
            float bb = b1[col];
#pragma unroll
            for (int r = 0; r < 4; ++r) {
                float x = acc[nt][r] + bb;
                x = x / (1.f + __expf(-x));
                hsm[lrow0 + r][col] = f32_to_bf16(x);
            }
        }
    }
    __syncthreads();

    bf16x8 af2[4];
#pragma unroll
    for (int kt = 0; kt < 4; ++kt)
        af2[kt] = *(const bf16x8*)&hsm[wv * 16 + lr][kt * 32 + lg * 8];

    // ---- stage 2: 3 chunks together, direct pv write ----
    const int crow = m0 + lg * 4;
#pragma unroll
    for (int nt = 0; nt < 8; ++nt) {
        f32x4 a0 = (f32x4){0.f, 0.f, 0.f, 0.f};
        f32x4 a1 = (f32x4){0.f, 0.f, 0.f, 0.f};
        f32x4 a2 = (f32x4){0.f, 0.f, 0.f, 0.f};
#pragma unroll
        for (int kt = 0; kt < 4; ++kt) {
            const int k0 = kt * 32 + lg * 8;
            const size_t wrow = (size_t)(nt * 16 + lr) * 128 + k0;
            bf16x8 bf0 = *(const bf16x8*)(W2t + wrow);
            bf16x8 bf1 = *(const bf16x8*)(W2t + (size_t)128 * 128 + wrow);
            bf16x8 bf2 = *(const bf16x8*)(W2t + (size_t)256 * 128 + wrow);
            a0 = __builtin_amdgcn_mfma_f32_16x16x32_bf16(af2[kt], bf0, a0, 0, 0, 0);
            a1 = __builtin_amdgcn_mfma_f32_16x16x32_bf16(af2[kt], bf1, a1, 0, 0, 0);
            a2 = __builtin_amdgcn_mfma_f32_16x16x32_bf16(af2[kt], bf2, a2, 0, 0, 0);
        }

        const int col = nt * 16 + lr;
        const float bb0 = b2[col], bb1 = b2[128 + col], bb2 = b2[256 + col];
#pragma unroll
        for (int r = 0; r < 4; ++r) {
            int m = crow + r;
            if (m < N_NODES_C) {
                const float* vr = v + (size_t)m * 384;
                unsigned p0 = f32_to_bf16(a0[r] + bb0);
                unsigned p1 = f32_to_bf16(a1[r] + bb1);
                unsigned p2 = f32_to_bf16(a2[r] + bb2);
                unsigned v0 = f32_to_bf16(vr[col]);
                unsigned v1 = f32_to_bf16(vr[128 + col]);
                unsigned v2 = f32_to_bf16(vr[256 + col]);
                uint4 val;
                val.x = p0 | (p1 << 16);
                val.y = p2 | (v0 << 16);
                val.z = v1 | (v2 << 16);
                val.w = 0;
                *(uint4*)((char*)pv + (size_t)m * 2048 + (size_t)col * 16) = val;
            }
        }
    }
}

// ---------------------------------------------------------------------------
// CSR build: histogram -> 3-kernel parallel scan -> fill
// ---------------------------------------------------------------------------
__global__ __launch_bounds__(256) void count_kernel(
    const int* __restrict__ dst, int* __restrict__ counts)
{
    int e = blockIdx.x * 256 + threadIdx.x;
    if (e < N_EDGES_C) atomicAdd(counts + dst[e], 1);
}

__global__ __launch_bounds__(256) void scan1_kernel(
    const int* __restrict__ counts, int* __restrict__ row_tmp,
    int* __restrict__ partial)
{
    __shared__ int sm[256];
    const int t = threadIdx.x;
    const int idx = blockIdx.x * 256 + t;
    int c = (idx < N_NODES_C) ? counts[idx] : 0;
    int x = c;
    sm[t] = x;
    __syncthreads();
#pragma unroll
    for (int off = 1; off < 256; off <<= 1) {
        int y = (t >= off) ? sm[t - off] : 0;
        __syncthreads();
        x += y;
        sm[t] = x;
        __syncthreads();
    }
    if (idx < N_NODES_C) row_tmp[idx] = x - c;
    if (t == 255) partial[blockIdx.x] = x;
}

__global__ __launch_bounds__(256) void scan2_kernel(
    const int* __restrict__ partial, int* __restrict__ poffs)
{
    __shared__ int sm[256];
    const int t = threadIdx.x;
    int c = (t < SC_BLK) ? partial[t] : 0;
    int x = c;
    sm[t] = x;
    __syncthreads();
#pragma unroll
    for (int off = 1; off < 256; off <<= 1) {
        int y = (t >= off) ? sm[t - off] : 0;
        __syncthreads();
        x += y;
        sm[t] = x;
        __syncthreads();
    }
    if (t < SC_BLK) poffs[t] = x - c;
}

__global__ __launch_bounds__(256) void scan3_kernel(
    const int* __restrict__ row_tmp, const int* __restrict__ poffs,
    int* __restrict__ row_ptr, int* __restrict__ row_fill)
{
    const int idx = blockIdx.x * 256 + threadIdx.x;
    if (idx < N_NODES_C) {
        int rp = row_tmp[idx] + poffs[blockIdx.x];
        row_ptr[idx]  = rp;
        row_fill[idx] = rp;
    }
    if (idx == 0) row_ptr[N_NODES_C] = N_EDGES_C;
}

// ---------------------------------------------------------------------------
// Edge precompute into dst-sorted slots; 64B (16-float) record per edge:
//   q0 = {dx, dy, dz, fcut}
//   q1..q2, q3.xy = rbf[k]*invd*fcut as 10 packed half2
//   q3.z = bitcast(src), q3.w = 0
// ---------------------------------------------------------------------------
__global__ __launch_bounds__(256) void fill_kernel(
    const float* __restrict__ rel_pos, const int* __restrict__ src,
    const int* __restrict__ dst, int* __restrict__ row_fill,
    float* __restrict__ e_meta)
{
    int e = blockIdx.x * 256 + threadIdx.x;
    if (e >= N_EDGES_C) return;

    int pos = atomicAdd(row_fill + dst[e], 1);

    float x = rel_pos[3 * e + 0];
    float y = rel_pos[3 * e + 1];
    float z = rel_pos[3 * e + 2];
    float d = sqrtf(x * x + y * y + z * z);
    float invd = 1.0f / d;

    float s1 = 0.f, c1 = 0.f, fcut = 0.f, amp = 0.f;
    if (d < CUT) {
        sincosf((3.14159265358979f / CUT) * d, &s1, &c1);
        fcut = 0.5f * (c1 + 1.0f);
        amp  = invd * fcut;
    }

    float rb[NRBF];
    float sk = s1, ck = c1;
#pragma unroll
    for (int k = 0; k < NRBF; ++k) {
        rb[k] = sk * amp;
        float sn = sk * c1 + ck * s1;
        ck = ck * c1 - sk * s1;
        sk = sn;
    }

    unsigned pk[10];
#pragma unroll
    for (int kp = 0; kp < 10; ++kp)
        pk[kp] = (unsigned)f16_bits(rb[2 * kp]) | ((unsigned)f16_bits(rb[2 * kp + 1]) << 16);

    float4* mp = (float4*)(e_meta + (size_t)pos * 16);
    mp[0] = make_float4(x * invd, y * invd, z * invd, fcut);
    mp[1] = make_float4(__uint_as_float(pk[0]), __uint_as_float(pk[1]),
                        __uint_as_float(pk[2]), __uint_as_float(pk[3]));
    mp[2] = make_float4(__uint_as_float(pk[4]), __uint_as_float(pk[5]),
                        __uint_as_float(pk[6]), __uint_as_float(pk[7]));
    mp[3] = make_float4(__uint_as_float(pk[8]), __uint_as_float(pk[9]),
                        __int_as_float(src[e]), 0.f);
}

// ---------------------------------------------------------------------------
// Gather: per block (128 threads) a contiguous dst-sorted edge range; 64B meta
// records batch-staged via LDS (BATCH=32 = one float4/thread, double-buffered);
// pv gathered as ONE aligned dwordx4 per edge per lane, depth-2 ping-pong.
// Wr held as 30 packed-f16 uints/lane (asm-pinned vs rematerialization —
// round-11 lesson: launch_bounds min-waves only CAPS VGPRs, never raises;
// the fix is shrinking the working set + pinning). Dot via v_dot2_f32_f16.
// ---------------------------------------------------------------------------
#define COMPUTE_E(M_, U)                                                       \
    {                                                                          \
        const float4 m0 = *(const float4*)(M_);                                \
        const unsigned* mu_ = (const unsigned*)((M_) + 4);                     \
        float w0 = m0.w * br0, w1 = m0.w * br1, w2 = m0.w * br2;               \
        _Pragma("unroll")                                                      \
        for (int kp = 0; kp < 10; ++kp) {                                      \
            f16x2 rh = u2h2(mu_[kp]);                                          \
            w0 = __builtin_amdgcn_fdot2(rh, u2h2(wrp0[kp]), w0, false);        \
            w1 = __builtin_amdgcn_fdot2(rh, u2h2(wrp1[kp]), w1, false);        \
            w2 = __builtin_amdgcn_fdot2(rh, u2h2(wrp2[kp]), w2, false);        \
        }                                                                      \
        float P0 = bf16_to_f32((unsigned short)((U).x & 0xFFFFu));             \
        float P1 = bf16_to_f32((unsigned short)((U).x >> 16));                 \
        float P2 = bf16_to_f32((unsigned short)((U).y & 0xFFFFu));             \
        float V0 = bf16_to_f32((unsigned short)((U).y >> 16));                 \
        float V1 = bf16_to_f32((unsigned short)((U).z & 0xFFFFu));             \
        float V2 = bf16_to_f32((unsigned short)((U).z >> 16));                 \
        float sv = w0 * P0;                                                    \
        float ss = w1 * P1;                                                    \
        float sr = w2 * P2;                                                    \
        acc_s  += ss;                                                          \
        acc_v0 += V0 * sv + m0.x * sr;                                         \
        acc_v1 += V1 * sv + m0.y * sr;                                         \
        acc_v2 += V2 * sv + m0.z * sr;                                         \
    }

#define LOADPV(U, SI)                                                          \
    U = *(const uint4*)((const char*)pv + (size_t)(SI) * 2048 + (size_t)f * 16);

#define STORE_NODE(N_, AS, A0, A1, A2)                                         \
    {                                                                          \
        out_s[(size_t)(N_) * 128 + f] = AS;                                    \
        out_v[(size_t)(N_) * 384 +       f] = A0;                              \
        out_v[(size_t)(N_) * 384 + 128 + f] = A1;                              \
        out_v[(size_t)(N_) * 384 + 256 + f] = A2;                              \
    }

#define BOUNDARY(GE)                                                           \
    if ((GE) + 1 == end_cur) {                                                 \
        STORE_NODE(cur, acc_s, acc_v0, acc_v1, acc_v2);                        \
        acc_s = acc_v0 = acc_v1 = acc_v2 = 0.f;                                \
        ++cur;                                                                 \
        while (cur < nhi) {                                                    \
            int ne_ = row_ptr[cur + 1];                                        \
            if (ne_ != (GE) + 1) { end_cur = ne_; break; }                     \
            STORE_NODE(cur, 0.f, 0.f, 0.f, 0.f);                               \
            ++cur;                                                             \
        }                                                                      \
    }

__global__ __launch_bounds__(128) void gather_packed_kernel(
    const unsigned short* __restrict__ pv, const unsigned* __restrict__ wrh,
    const float* __restrict__ br, const int* __restrict__ row_ptr,
    const float* __restrict__ e_meta,
    float* __restrict__ out_v, float* __restrict__ out_s)
{
    __shared__ float meta_lds[2][BATCH * 16];

    const int f = threadIdx.x;               // 0..127 feature lane
    const int gid = blockIdx.x;
    const int chunk = (N_NODES_C + GBLOCKS - 1) / GBLOCKS;
    const int nlo = gid * chunk;
    if (nlo >= N_NODES_C) return;
    const int nhi = min(nlo + chunk, N_NODES_C);

    // per-lane Wr f16-pairs -> 30 registers, pinned against remat
    unsigned wrp0[10], wrp1[10], wrp2[10];
    {
        const unsigned* wp = wrh + (size_t)f * 30;
#pragma unroll
        for (int i = 0; i < 10; ++i) {
            wrp0[i] = wp[i];
            wrp1[i] = wp[10 + i];
            wrp2[i] = wp[20 + i];
        }
#pragma unroll
        for (int i = 0; i < 10; ++i)
            asm volatile("" : "+v"(wrp0[i]), "+v"(wrp1[i]), "+v"(wrp2[i]));
    }
    const float br0 = br[f], br1 = br[128 + f], br2 = br[256 + f];

    const int gbeg = row_ptr[nlo];
    const int gend = row_ptr[nhi];
    const int nedge = gend - gbeg;

    float acc_s = 0.f, acc_v0 = 0.f, acc_v1 = 0.f, acc_v2 = 0.f;

    int cur = nlo;
    while (cur < nhi && row_ptr[cur + 1] == gbeg) {
        STORE_NODE(cur, 0.f, 0.f, 0.f, 0.f);
        ++cur;
    }
    int end_cur = (cur < nhi) ? row_ptr[cur + 1] : gbeg;

    // stage batch 0: 32 records x 64B = 128 float4 (one per thread)
    if (nedge > 0) {
        const float4* src0 = (const float4*)(e_meta + (size_t)gbeg * 16);
        ((float4*)meta_lds[0])[threadIdx.x] = src0[threadIdx.x];
    }
    __syncthreads();

    const int total_batches = (nedge + BATCH - 1) / BATCH;
    for (int b = 0; b < total_batches; ++b) {
        const int bstart = b * BATCH;
        const int bcount = min(BATCH, nedge - bstart);
        const bool have_next = (b + 1 < total_batches);

        float4 st;
        if (have_next)
            st = ((const float4*)(e_meta + (size_t)(gbeg + bstart + BATCH) * 16))[threadIdx.x];

        const float* Mb = meta_lds[b & 1];

        uint4 uA, uB;
        {
            int si = ((const int*)Mb)[14];
            LOADPV(uA, si);
        }

        int t = 0;
        while (t < bcount) {
            if (t + 1 < bcount) {
                int si = ((const int*)(Mb + (t + 1) * 16))[14];
                LOADPV(uB, si);
            }
            COMPUTE_E(Mb + t * 16, uA);
            BOUNDARY(gbeg + bstart + t);
            ++t; if (t >= bcount) break;

            if (t + 1 < bcount) {
                int si = ((const int*)(Mb + (t + 1) * 16))[14];
                LOADPV(uA, si);
            }
            COMPUTE_E(Mb + t * 16, uB);
            BOUNDARY(gbeg + bstart + t);
            ++t;
        }

        if (have_next) ((float4*)meta_lds[(b + 1) & 1])[threadIdx.x] = st;
        __syncthreads();
    }
}

// ---------------------------------------------------------------------------
extern "C" void kernel_launch(void* const* d_in, const int* in_sizes, int n_in,
                              void* d_out, int out_size, void* d_ws, size_t ws_size,
                              hipStream_t stream)
{
    const float* s  = (const float*)d_in[0];
    const float* v  = (const float*)d_in[1];
    const float* rp = (const float*)d_in[2];
    const float* W1 = (const float*)d_in[3];
    const float* b1 = (const float*)d_in[4];
    const float* W2 = (const float*)d_in[5];
    const float* b2 = (const float*)d_in[6];
    const float* Wr = (const float*)d_in[7];
    const float* br = (const float*)d_in[8];
    const int* src  = (const int*)d_in[9];
    const int* dst  = (const int*)d_in[10];

    float* out   = (float*)d_out;
    float* out_v = out;                                    // 50000*3*128
    float* out_s = out + (size_t)N_NODES_C * 3 * FDIM;     // 50000*128

    // workspace layout (~117 MB total)
    char* ws = (char*)d_ws;
    float* e_meta = (float*)ws;                 ws += ((size_t)N_EDGES_C * 16 + 256) * sizeof(float);
    unsigned short* W1t = (unsigned short*)ws;  ws += (size_t)128 * 128 * sizeof(unsigned short);
    unsigned short* W2t = (unsigned short*)ws;  ws += (size_t)384 * 128 * sizeof(unsigned short);
    unsigned* wrh = (unsigned*)ws;              ws += (size_t)128 * 30 * sizeof(unsigned);
    int* counts   = (int*)ws;                   ws += (size_t)N_NODES_C * sizeof(int);
    int* row_ptr  = (int*)ws;                   ws += (size_t)(N_NODES_C + 4) * sizeof(int);
    int* row_fill = (int*)ws;                   ws += (size_t)N_NODES_C * sizeof(int);
    int* row_tmp  = (int*)ws;                   ws += (size_t)N_NODES_C * sizeof(int);
    int* partial  = (int*)ws;                   ws += (size_t)256 * sizeof(int);
    int* poffs    = (int*)ws;                   ws += (size_t)256 * sizeof(int);
    unsigned short* pv = (unsigned short*)ws;   // 50000 * 2048B = 102.4 MB

    hipMemsetAsync(counts, 0, (size_t)N_NODES_C * sizeof(int), stream);

    count_kernel<<<(N_EDGES_C + 255) / 256, 256, 0, stream>>>(dst, counts);
    scan1_kernel<<<SC_BLK, 256, 0, stream>>>(counts, row_tmp, partial);
    scan2_kernel<<<1, 256, 0, stream>>>(partial, poffs);
    scan3_kernel<<<SC_BLK, 256, 0, stream>>>(row_tmp, poffs, row_ptr, row_fill);
    fill_kernel<<<(N_EDGES_C + 255) / 256, 256, 0, stream>>>(rp, src, dst, row_fill, e_meta);

    prep_w_kernel<<<256, 256, 0, stream>>>(W1, W2, W1t, W2t);
    prep_wr_kernel<<<15, 256, 0, stream>>>(Wr, wrh);
    mlp12pv_kernel<<<(N_NODES_C + 63) / 64, 256, 0, stream>>>(s, W1t, b1, W2t, b2, v, pv);

    gather_packed_kernel<<<GBLOCKS, 128, 0, stream>>>(pv, wrh, br, row_ptr,
                                                      e_meta, out_v, out_s);
}

// Round 13
// 243.989 us; speedup vs baseline: 1.2672x; 1.0275x over previous
//
#include <hip/hip_runtime.h>
#include <math.h>

#define N_NODES_C 50000
#define N_EDGES_C 200000
#define FDIM 128
#define NRBF 20
#define CUT 5.0f
#define SC_BLK 196   // ceil(50000/256)
#define GBLOCKS 4096
#define BATCH 32     // edges staged per LDS batch (32 x 64B = 2KB = 128 float4)

typedef short  bf16x8 __attribute__((ext_vector_type(8)));
typedef float  f32x4  __attribute__((ext_vector_type(4)));
typedef _Float16 f16x2 __attribute__((ext_vector_type(2)));

__device__ __forceinline__ unsigned short f32_to_bf16(float f) {
    unsigned u = __float_as_uint(f);
    unsigned r = (u + 0x7FFFu + ((u >> 16) & 1u)) >> 16;   // RNE
    return (unsigned short)r;
}
__device__ __forceinline__ float bf16_to_f32(unsigned short h) {
    return __uint_as_float(((unsigned)h) << 16);
}
__device__ __forceinline__ unsigned short f16_bits(float x) {
    _Float16 h = (_Float16)x;
    unsigned short b;
    __builtin_memcpy(&b, &h, 2);
    return b;
}
__device__ __forceinline__ f16x2 u2h2(unsigned u) {
    f16x2 r;
    __builtin_memcpy(&r, &u, 4);
    return r;
}
__device__ __forceinline__ bf16x8 pack_bf16x8(float4 a, float4 b) {
    bf16x8 r;
    r[0] = (short)f32_to_bf16(a.x); r[1] = (short)f32_to_bf16(a.y);
    r[2] = (short)f32_to_bf16(a.z); r[3] = (short)f32_to_bf16(a.w);
    r[4] = (short)f32_to_bf16(b.x); r[5] = (short)f32_to_bf16(b.y);
    r[6] = (short)f32_to_bf16(b.z); r[7] = (short)f32_to_bf16(b.w);
    return r;
}

// ---------------------------------------------------------------------------
// Weight prep: W1t[n][k] = bf16(W1[k][n]) (128x128), W2t[n][k] = bf16(W2[k][n])
// ---------------------------------------------------------------------------
__global__ __launch_bounds__(256) void prep_w_kernel(
    const float* __restrict__ W1, const float* __restrict__ W2,
    unsigned short* __restrict__ W1t, unsigned short* __restrict__ W2t)
{
    int i = blockIdx.x * 256 + threadIdx.x;
    if (i < 128 * 128) {
        int n = i >> 7, k = i & 127;
        W1t[i] = f32_to_bf16(W1[k * 128 + n]);
    }
    int j = i - 128 * 128;
    if (j >= 0 && j < 384 * 128) {
        int n = j >> 7, k = j & 127;
        W2t[j] = f32_to_bf16(W2[k * 384 + n]);
    }
}

// ---------------------------------------------------------------------------
// Wr prep: per-lane packed f16 pairs.
// wrh[f*30 + sec*10 + kp] = half2{ Wr[2kp][sec*128+f], Wr[2kp+1][sec*128+f] }
// ---------------------------------------------------------------------------
__global__ __launch_bounds__(256) void prep_wr_kernel(
    const float* __restrict__ Wr, unsigned* __restrict__ wrh)
{
    int idx = blockIdx.x * 256 + threadIdx.x;
    if (idx >= 128 * 30) return;
    int f  = idx / 30;
    int r  = idx % 30;
    int sec = r / 10, kp = r % 10;
    int col = sec * 128 + f;
    unsigned lo = f16_bits(Wr[(2 * kp)     * 384 + col]);
    unsigned hi = f16_bits(Wr[(2 * kp + 1) * 384 + col]);
    wrh[idx] = lo | (hi << 16);
}

// ---------------------------------------------------------------------------
// Fused MLP -> pv (MFMA), round-13 rebuild for latency (round-12 lesson:
// 782 blocks = 3/CU + 96 scalar v-loads/thread = 115us of idle pipes):
//  - 32-row tile, 128 threads, grid 1563 (2x blocks)
//  - stage2 phi triples staged to 3 LDS planes [32][132] (25.3KB, reuses
//    stage-1 h region after a barrier)
//  - epilogue: thread f owns column f -> v reads are 3 coalesced 512B
//    wave-streams, pv writes contiguous 2KB rows. No scalar gathers.
// ---------------------------------------------------------------------------
__global__ __launch_bounds__(128) void mlp12pv_kernel(
    const float* __restrict__ s, const unsigned short* __restrict__ W1t,
    const float* __restrict__ b1, const unsigned short* __restrict__ W2t,
    const float* __restrict__ b2, const float* __restrict__ v,
    unsigned short* __restrict__ pv)
{
    __shared__ unsigned short smem[3 * 32 * 132];   // 25.3 KB
    unsigned short (*hsm)[136] = (unsigned short (*)[136])smem;  // 32x136 fits

    const int tid = threadIdx.x;
    const int wv = tid >> 6, lane = tid & 63;       // 2 waves
    const int m0 = blockIdx.x * 32 + wv * 16;
    const int lr = lane & 15, lg = lane >> 4;
    int arow = m0 + lr; if (arow >= N_NODES_C) arow = N_NODES_C - 1;

    // ---- stage 1: h = silu(s @ W1 + b1) -> hsm ----
    {
        f32x4 acc[8];
#pragma unroll
        for (int nt = 0; nt < 8; ++nt) acc[nt] = (f32x4){0.f, 0.f, 0.f, 0.f};

#pragma unroll
        for (int kt = 0; kt < 4; ++kt) {
            const int k0 = kt * 32 + lg * 8;
            const float4* ap = (const float4*)(s + (size_t)arow * 128 + k0);
            bf16x8 af = pack_bf16x8(ap[0], ap[1]);
#pragma unroll
            for (int nt = 0; nt < 8; ++nt) {
                bf16x8 bf = *(const bf16x8*)(W1t + (size_t)(nt * 16 + lr) * 128 + k0);
                acc[nt] = __builtin_amdgcn_mfma_f32_16x16x32_bf16(af, bf, acc[nt], 0, 0, 0);
            }
        }

        const int lrow0 = wv * 16 + lg * 4;
#pragma unroll
        for (int nt = 0; nt < 8; ++nt) {
            int col = nt * 16 + lr;
            float bb = b1[col];
#pragma unroll
            for (int r = 0; r < 4; ++r) {
                float x = acc[nt][r] + bb;
                x = x / (1.f + __expf(-x));
                hsm[lrow0 + r][col] = f32_to_bf16(x);
            }
        }
    }
    __syncthreads();

    bf16x8 af2[4];
#pragma unroll
    for (int kt = 0; kt < 4; ++kt)
        af2[kt] = *(const bf16x8*)&hsm[wv * 16 + lr][kt * 32 + lg * 8];
    __syncthreads();   // h fully read before smem reused as phi planes

    // ---- stage 2: 3 chunks together -> LDS planes [c][row][col] ----
    const int crow_l = wv * 16 + lg * 4;
#pragma unroll
    for (int nt = 0; nt < 8; ++nt) {
        f32x4 a0 = (f32x4){0.f, 0.f, 0.f, 0.f};
        f32x4 a1 = (f32x4){0.f, 0.f, 0.f, 0.f};
        f32x4 a2 = (f32x4){0.f, 0.f, 0.f, 0.f};
#pragma unroll
        for (int kt = 0; kt < 4; ++kt) {
            const int k0 = kt * 32 + lg * 8;
            const size_t wrow = (size_t)(nt * 16 + lr) * 128 + k0;
            bf16x8 bf0 = *(const bf16x8*)(W2t + wrow);
            bf16x8 bf1 = *(const bf16x8*)(W2t + (size_t)128 * 128 + wrow);
            bf16x8 bf2 = *(const bf16x8*)(W2t + (size_t)256 * 128 + wrow);
            a0 = __builtin_amdgcn_mfma_f32_16x16x32_bf16(af2[kt], bf0, a0, 0, 0, 0);
            a1 = __builtin_amdgcn_mfma_f32_16x16x32_bf16(af2[kt], bf1, a1, 0, 0, 0);
            a2 = __builtin_amdgcn_mfma_f32_16x16x32_bf16(af2[kt], bf2, a2, 0, 0, 0);
        }

        const int col = nt * 16 + lr;
        const float bb0 = b2[col], bb1 = b2[128 + col], bb2 = b2[256 + col];
#pragma unroll
        for (int r = 0; r < 4; ++r) {
            int row = crow_l + r;
            smem[             row * 132 + col] = f32_to_bf16(a0[r] + bb0);
            smem[32 * 132  +  row * 132 + col] = f32_to_bf16(a1[r] + bb1);
            smem[64 * 132  +  row * 132 + col] = f32_to_bf16(a2[r] + bb2);
        }
    }
    __syncthreads();

    // ---- pack epilogue: coalesced v streams + contiguous pv rows ----
    {
        const int f = tid;   // 0..127 = column
#pragma unroll 4
        for (int ln = 0; ln < 32; ++ln) {
            int gn = blockIdx.x * 32 + ln;
            if (gn < N_NODES_C) {
                const float* vr = v + (size_t)gn * 384;
                unsigned p0 = smem[             ln * 132 + f];
                unsigned p1 = smem[32 * 132  +  ln * 132 + f];
                unsigned p2 = smem[64 * 132  +  ln * 132 + f];
                unsigned v0 = f32_to_bf16(vr[f]);
                unsigned v1 = f32_to_bf16(vr[128 + f]);
                unsigned v2 = f32_to_bf16(vr[256 + f]);
                uint4 val;
                val.x = p0 | (p1 << 16);
                val.y = p2 | (v0 << 16);
                val.z = v1 | (v2 << 16);
                val.w = 0;
                *(uint4*)((char*)pv + (size_t)gn * 2048 + (size_t)f * 16) = val;
            }
        }
    }
}

// ---------------------------------------------------------------------------
// CSR build: histogram -> 3-kernel parallel scan -> fill
// ---------------------------------------------------------------------------
__global__ __launch_bounds__(256) void count_kernel(
    const int* __restrict__ dst, int* __restrict__ counts)
{
    int e = blockIdx.x * 256 + threadIdx.x;
    if (e < N_EDGES_C) atomicAdd(counts + dst[e], 1);
}

__global__ __launch_bounds__(256) void scan1_kernel(
    const int* __restrict__ counts, int* __restrict__ row_tmp,
    int* __restrict__ partial)
{
    __shared__ int sm[256];
    const int t = threadIdx.x;
    const int idx = blockIdx.x * 256 + t;
    int c = (idx < N_NODES_C) ? counts[idx] : 0;
    int x = c;
    sm[t] = x;
    __syncthreads();
#pragma unroll
    for (int off = 1; off < 256; off <<= 1) {
        int y = (t >= off) ? sm[t - off] : 0;
        __syncthreads();
        x += y;
        sm[t] = x;
        __syncthreads();
    }
    if (idx < N_NODES_C) row_tmp[idx] = x - c;
    if (t == 255) partial[blockIdx.x] = x;
}

__global__ __launch_bounds__(256) void scan2_kernel(
    const int* __restrict__ partial, int* __restrict__ poffs)
{
    __shared__ int sm[256];
    const int t = threadIdx.x;
    int c = (t < SC_BLK) ? partial[t] : 0;
    int x = c;
    sm[t] = x;
    __syncthreads();
#pragma unroll
    for (int off = 1; off < 256; off <<= 1) {
        int y = (t >= off) ? sm[t - off] : 0;
        __syncthreads();
        x += y;
        sm[t] = x;
        __syncthreads();
    }
    if (t < SC_BLK) poffs[t] = x - c;
}

__global__ __launch_bounds__(256) void scan3_kernel(
    const int* __restrict__ row_tmp, const int* __restrict__ poffs,
    int* __restrict__ row_ptr, int* __restrict__ row_fill)
{
    const int idx = blockIdx.x * 256 + threadIdx.x;
    if (idx < N_NODES_C) {
        int rp = row_tmp[idx] + poffs[blockIdx.x];
        row_ptr[idx]  = rp;
        row_fill[idx] = rp;
    }
    if (idx == 0) row_ptr[N_NODES_C] = N_EDGES_C;
}

// ---------------------------------------------------------------------------
// Edge precompute into dst-sorted slots; 64B (16-float) record per edge:
//   q0 = {dx, dy, dz, fcut}
//   q1..q2, q3.xy = rbf[k]*invd*fcut as 10 packed half2
//   q3.z = bitcast(src), q3.w = 0
// ---------------------------------------------------------------------------
__global__ __launch_bounds__(256) void fill_kernel(
    const float* __restrict__ rel_pos, const int* __restrict__ src,
    const int* __restrict__ dst, int* __restrict__ row_fill,
    float* __restrict__ e_meta)
{
    int e = blockIdx.x * 256 + threadIdx.x;
    if (e >= N_EDGES_C) return;

    int pos = atomicAdd(row_fill + dst[e], 1);

    float x = rel_pos[3 * e + 0];
    float y = rel_pos[3 * e + 1];
    float z = rel_pos[3 * e + 2];
    float d = sqrtf(x * x + y * y + z * z);
    float invd = 1.0f / d;

    float s1 = 0.f, c1 = 0.f, fcut = 0.f, amp = 0.f;
    if (d < CUT) {
        sincosf((3.14159265358979f / CUT) * d, &s1, &c1);
        fcut = 0.5f * (c1 + 1.0f);
        amp  = invd * fcut;
    }

    float rb[NRBF];
    float sk = s1, ck = c1;
#pragma unroll
    for (int k = 0; k < NRBF; ++k) {
        rb[k] = sk * amp;
        float sn = sk * c1 + ck * s1;
        ck = ck * c1 - sk * s1;
        sk = sn;
    }

    unsigned pk[10];
#pragma unroll
    for (int kp = 0; kp < 10; ++kp)
        pk[kp] = (unsigned)f16_bits(rb[2 * kp]) | ((unsigned)f16_bits(rb[2 * kp + 1]) << 16);

    float4* mp = (float4*)(e_meta + (size_t)pos * 16);
    mp[0] = make_float4(x * invd, y * invd, z * invd, fcut);
    mp[1] = make_float4(__uint_as_float(pk[0]), __uint_as_float(pk[1]),
                        __uint_as_float(pk[2]), __uint_as_float(pk[3]));
    mp[2] = make_float4(__uint_as_float(pk[4]), __uint_as_float(pk[5]),
                        __uint_as_float(pk[6]), __uint_as_float(pk[7]));
    mp[3] = make_float4(__uint_as_float(pk[8]), __uint_as_float(pk[9]),
                        __int_as_float(src[e]), 0.f);
}

// ---------------------------------------------------------------------------
// Gather (UNCHANGED from round 12 — it dropped out of top-5): 64B meta staged
// via LDS, one aligned dwordx4 pv gather per edge, f16-dot2 with 30 pinned
// packed-Wr registers.
// ---------------------------------------------------------------------------
#define COMPUTE_E(M_, U)                                                       \
    {                                                                          \
        const float4 m0 = *(const float4*)(M_);                                \
        const unsigned* mu_ = (const unsigned*)((M_) + 4);                     \
        float w0 = m0.w * br0, w1 = m0.w * br1, w2 = m0.w * br2;               \
        _Pragma("unroll")                                                      \
        for (int kp = 0; kp < 10; ++kp) {                                      \
            f16x2 rh = u2h2(mu_[kp]);                                          \
            w0 = __builtin_amdgcn_fdot2(rh, u2h2(wrp0[kp]), w0, false);        \
            w1 = __builtin_amdgcn_fdot2(rh, u2h2(wrp1[kp]), w1, false);        \
            w2 = __builtin_amdgcn_fdot2(rh, u2h2(wrp2[kp]), w2, false);        \
        }                                                                      \
        float P0 = bf16_to_f32((unsigned short)((U).x & 0xFFFFu));             \
        float P1 = bf16_to_f32((unsigned short)((U).x >> 16));                 \
        float P2 = bf16_to_f32((unsigned short)((U).y & 0xFFFFu));             \
        float V0 = bf16_to_f32((unsigned short)((U).y >> 16));                 \
        float V1 = bf16_to_f32((unsigned short)((U).z & 0xFFFFu));             \
        float V2 = bf16_to_f32((unsigned short)((U).z >> 16));                 \
        float sv = w0 * P0;                                                    \
        float ss = w1 * P1;                                                    \
        float sr = w2 * P2;                                                    \
        acc_s  += ss;                                                          \
        acc_v0 += V0 * sv + m0.x * sr;                                         \
        acc_v1 += V1 * sv + m0.y * sr;                                         \
        acc_v2 += V2 * sv + m0.z * sr;                                         \
    }

#define LOADPV(U, SI)                                                          \
    U = *(const uint4*)((const char*)pv + (size_t)(SI) * 2048 + (size_t)f * 16);

#define STORE_NODE(N_, AS, A0, A1, A2)                                         \
    {                                                                          \
        out_s[(size_t)(N_) * 128 + f] = AS;                                    \
        out_v[(size_t)(N_) * 384 +       f] = A0;                              \
        out_v[(size_t)(N_) * 384 + 128 + f] = A1;                              \
        out_v[(size_t)(N_) * 384 + 256 + f] = A2;                              \
    }

#define BOUNDARY(GE)                                                           \
    if ((GE) + 1 == end_cur) {                                                 \
        STORE_NODE(cur, acc_s, acc_v0, acc_v1, acc_v2);                        \
        acc_s = acc_v0 = acc_v1 = acc_v2 = 0.f;                                \
        ++cur;                                                                 \
        while (cur < nhi) {                                                    \
            int ne_ = row_ptr[cur + 1];                                        \
            if (ne_ != (GE) + 1) { end_cur = ne_; break; }                     \
            STORE_NODE(cur, 0.f, 0.f, 0.f, 0.f);                               \
            ++cur;                                                             \
        }                                                                      \
    }

__global__ __launch_bounds__(128) void gather_packed_kernel(
    const unsigned short* __restrict__ pv, const unsigned* __restrict__ wrh,
    const float* __restrict__ br, const int* __restrict__ row_ptr,
    const float* __restrict__ e_meta,
    float* __restrict__ out_v, float* __restrict__ out_s)
{
    __shared__ float meta_lds[2][BATCH * 16];

    const int f = threadIdx.x;               // 0..127 feature lane
    const int gid = blockIdx.x;
    const int chunk = (N_NODES_C + GBLOCKS - 1) / GBLOCKS;
    const int nlo = gid * chunk;
    if (nlo >= N_NODES_C) return;
    const int nhi = min(nlo + chunk, N_NODES_C);

    // per-lane Wr f16-pairs -> 30 registers, pinned against remat
    unsigned wrp0[10], wrp1[10], wrp2[10];
    {
        const unsigned* wp = wrh + (size_t)f * 30;
#pragma unroll
        for (int i = 0; i < 10; ++i) {
            wrp0[i] = wp[i];
            wrp1[i] = wp[10 + i];
            wrp2[i] = wp[20 + i];
        }
#pragma unroll
        for (int i = 0; i < 10; ++i)
            asm volatile("" : "+v"(wrp0[i]), "+v"(wrp1[i]), "+v"(wrp2[i]));
    }
    const float br0 = br[f], br1 = br[128 + f], br2 = br[256 + f];

    const int gbeg = row_ptr[nlo];
    const int gend = row_ptr[nhi];
    const int nedge = gend - gbeg;

    float acc_s = 0.f, acc_v0 = 0.f, acc_v1 = 0.f, acc_v2 = 0.f;

    int cur = nlo;
    while (cur < nhi && row_ptr[cur + 1] == gbeg) {
        STORE_NODE(cur, 0.f, 0.f, 0.f, 0.f);
        ++cur;
    }
    int end_cur = (cur < nhi) ? row_ptr[cur + 1] : gbeg;

    // stage batch 0: 32 records x 64B = 128 float4 (one per thread)
    if (nedge > 0) {
        const float4* src0 = (const float4*)(e_meta + (size_t)gbeg * 16);
        ((float4*)meta_lds[0])[threadIdx.x] = src0[threadIdx.x];
    }
    __syncthreads();

    const int total_batches = (nedge + BATCH - 1) / BATCH;
    for (int b = 0; b < total_batches; ++b) {
        const int bstart = b * BATCH;
        const int bcount = min(BATCH, nedge - bstart);
        const bool have_next = (b + 1 < total_batches);

        float4 st;
        if (have_next)
            st = ((const float4*)(e_meta + (size_t)(gbeg + bstart + BATCH) * 16))[threadIdx.x];

        const float* Mb = meta_lds[b & 1];

        uint4 uA, uB;
        {
            int si = ((const int*)Mb)[14];
            LOADPV(uA, si);
        }

        int t = 0;
        while (t < bcount) {
            if (t + 1 < bcount) {
                int si = ((const int*)(Mb + (t + 1) * 16))[14];
                LOADPV(uB, si);
            }
            COMPUTE_E(Mb + t * 16, uA);
            BOUNDARY(gbeg + bstart + t);
            ++t; if (t >= bcount) break;

            if (t + 1 < bcount) {
                int si = ((const int*)(Mb + (t + 1) * 16))[14];
                LOADPV(uA, si);
            }
            COMPUTE_E(Mb + t * 16, uB);
            BOUNDARY(gbeg + bstart + t);
            ++t;
        }

        if (have_next) ((float4*)meta_lds[(b + 1) & 1])[threadIdx.x] = st;
        __syncthreads();
    }
}

// ---------------------------------------------------------------------------
extern "C" void kernel_launch(void* const* d_in, const int* in_sizes, int n_in,
                              void* d_out, int out_size, void* d_ws, size_t ws_size,
                              hipStream_t stream)
{
    const float* s  = (const float*)d_in[0];
    const float* v  = (const float*)d_in[1];
    const float* rp = (const float*)d_in[2];
    const float* W1 = (const float*)d_in[3];
    const float* b1 = (const float*)d_in[4];
    const float* W2 = (const float*)d_in[5];
    const float* b2 = (const float*)d_in[6];
    const float* Wr = (const float*)d_in[7];
    const float* br = (const float*)d_in[8];
    const int* src  = (const int*)d_in[9];
    const int* dst  = (const int*)d_in[10];

    float* out   = (float*)d_out;
    float* out_v = out;                                    // 50000*3*128
    float* out_s = out + (size_t)N_NODES_C * 3 * FDIM;     // 50000*128

    // workspace layout (~117 MB total)
    char* ws = (char*)d_ws;
    float* e_meta = (float*)ws;                 ws += ((size_t)N_EDGES_C * 16 + 256) * sizeof(float);
    unsigned short* W1t = (unsigned short*)ws;  ws += (size_t)128 * 128 * sizeof(unsigned short);
    unsigned short* W2t = (unsigned short*)ws;  ws += (size_t)384 * 128 * sizeof(unsigned short);
    unsigned* wrh = (unsigned*)ws;              ws += (size_t)128 * 30 * sizeof(unsigned);
    int* counts   = (int*)ws;                   ws += (size_t)N_NODES_C * sizeof(int);
    int* row_ptr  = (int*)ws;                   ws += (size_t)(N_NODES_C + 4) * sizeof(int);
    int* row_fill = (int*)ws;                   ws += (size_t)N_NODES_C * sizeof(int);
    int* row_tmp  = (int*)ws;                   ws += (size_t)N_NODES_C * sizeof(int);
    int* partial  = (int*)ws;                   ws += (size_t)256 * sizeof(int);
    int* poffs    = (int*)ws;                   ws += (size_t)256 * sizeof(int);
    unsigned short* pv = (unsigned short*)ws;   // 50000 * 2048B = 102.4 MB

    hipMemsetAsync(counts, 0, (size_t)N_NODES_C * sizeof(int), stream);

    count_kernel<<<(N_EDGES_C + 255) / 256, 256, 0, stream>>>(dst, counts);
    scan1_kernel<<<SC_BLK, 256, 0, stream>>>(counts, row_tmp, partial);
    scan2_kernel<<<1, 256, 0, stream>>>(partial, poffs);
    scan3_kernel<<<SC_BLK, 256, 0, stream>>>(row_tmp, poffs, row_ptr, row_fill);
    fill_kernel<<<(N_EDGES_C + 255) / 256, 256, 0, stream>>>(rp, src, dst, row_fill, e_meta);

    prep_w_kernel<<<256, 256, 0, stream>>>(W1, W2, W1t, W2t);
    prep_wr_kernel<<<15, 256, 0, stream>>>(Wr, wrh);
    mlp12pv_kernel<<<(N_NODES_C + 31) / 32, 128, 0, stream>>>(s, W1t, b1, W2t, b2, v, pv);

    gather_packed_kernel<<<GBLOCKS, 128, 0, stream>>>(pv, wrh, br, row_ptr,
                                                      e_meta, out_v, out_s);
}

// Round 14
// 228.777 us; speedup vs baseline: 1.3515x; 1.0665x over previous
//
#include <hip/hip_runtime.h>
#include <math.h>

#define N_NODES_C 50000
#define N_EDGES_C 200000
#define FDIM 128
#define NRBF 20
#define CUT 5.0f
#define SC_BLK 196   // ceil(50000/256)
#define GBLOCKS 4096
#define BATCH 32     // edges staged per LDS batch (32 x 64B = 2KB = 128 float4)

typedef short  bf16x8 __attribute__((ext_vector_type(8)));
typedef float  f32x4  __attribute__((ext_vector_type(4)));
typedef _Float16 f16x2 __attribute__((ext_vector_type(2)));

__device__ __forceinline__ unsigned short f32_to_bf16(float f) {
    unsigned u = __float_as_uint(f);
    unsigned r = (u + 0x7FFFu + ((u >> 16) & 1u)) >> 16;   // RNE
    return (unsigned short)r;
}
__device__ __forceinline__ float bf16_to_f32(unsigned short h) {
    return __uint_as_float(((unsigned)h) << 16);
}
__device__ __forceinline__ unsigned short f16_bits(float x) {
    _Float16 h = (_Float16)x;
    unsigned short b;
    __builtin_memcpy(&b, &h, 2);
    return b;
}
__device__ __forceinline__ f16x2 u2h2(unsigned u) {
    f16x2 r;
    __builtin_memcpy(&r, &u, 4);
    return r;
}
__device__ __forceinline__ bf16x8 pack_bf16x8(float4 a, float4 b) {
    bf16x8 r;
    r[0] = (short)f32_to_bf16(a.x); r[1] = (short)f32_to_bf16(a.y);
    r[2] = (short)f32_to_bf16(a.z); r[3] = (short)f32_to_bf16(a.w);
    r[4] = (short)f32_to_bf16(b.x); r[5] = (short)f32_to_bf16(b.y);
    r[6] = (short)f32_to_bf16(b.z); r[7] = (short)f32_to_bf16(b.w);
    return r;
}

// ---------------------------------------------------------------------------
// Weight prep: W1t[n][k] = bf16(W1[k][n]) (128x128), W2t[n][k] = bf16(W2[k][n])
// ---------------------------------------------------------------------------
__global__ __launch_bounds__(256) void prep_w_kernel(
    const float* __restrict__ W1, const float* __restrict__ W2,
    unsigned short* __restrict__ W1t, unsigned short* __restrict__ W2t)
{
    int i = blockIdx.x * 256 + threadIdx.x;
    if (i < 128 * 128) {
        int n = i >> 7, k = i & 127;
        W1t[i] = f32_to_bf16(W1[k * 128 + n]);
    }
    int j = i - 128 * 128;
    if (j >= 0 && j < 384 * 128) {
        int n = j >> 7, k = j & 127;
        W2t[j] = f32_to_bf16(W2[k * 384 + n]);
    }
}

// ---------------------------------------------------------------------------
// Wr prep: per-lane packed f16 pairs.
// ---------------------------------------------------------------------------
__global__ __launch_bounds__(256) void prep_wr_kernel(
    const float* __restrict__ Wr, unsigned* __restrict__ wrh)
{
    int idx = blockIdx.x * 256 + threadIdx.x;
    if (idx >= 128 * 30) return;
    int f  = idx / 30;
    int r  = idx % 30;
    int sec = r / 10, kp = r % 10;
    int col = sec * 128 + f;
    unsigned lo = f16_bits(Wr[(2 * kp)     * 384 + col]);
    unsigned hi = f16_bits(Wr[(2 * kp + 1) * 384 + col]);
    wrh[idx] = lo | (hi << 16);
}

// ---------------------------------------------------------------------------
// MLP stage 1: h = silu(s @ W1 + b1). W1t staged in LDS ONCE per block
// (round-13 lesson: streaming s/v/pv traffic evicts weights from L2, so
// per-wave global B-loads serialize at L3 latency ~700cy -> 113us. LDS
// B-reads are ~12cy and eviction-immune). Row stride padded to 136 ushorts
// (272B, 16B-aligned) for minimum-aliasing ds_read_b128.
// ---------------------------------------------------------------------------
__global__ __launch_bounds__(256) void mlp1w_kernel(
    const float* __restrict__ s, const unsigned short* __restrict__ W1t,
    const float* __restrict__ b1, unsigned short* __restrict__ h)
{
    __shared__ unsigned short w1lds[128 * 136];   // 34.8 KB

    const int tid = threadIdx.x;
    // stage W1t (2048 float4) -> LDS
#pragma unroll
    for (int j = 0; j < 8; ++j) {
        int fi = tid + j * 256;           // float4 index 0..2047
        int row  = fi >> 4;               // 16 float4 per 128-ushort row
        int colq = fi & 15;
        *(float4*)&w1lds[row * 136 + colq * 8] =
            *(const float4*)(W1t + (size_t)fi * 8);
    }
    __syncthreads();

    const int wv = tid >> 6, lane = tid & 63;
    const int m0 = blockIdx.x * 64 + wv * 16;
    const int lr = lane & 15, lg = lane >> 4;
    int arow = m0 + lr; if (arow >= N_NODES_C) arow = N_NODES_C - 1;

    f32x4 acc[8];
#pragma unroll
    for (int nt = 0; nt < 8; ++nt) acc[nt] = (f32x4){0.f, 0.f, 0.f, 0.f};

#pragma unroll
    for (int kt = 0; kt < 4; ++kt) {
        const int k0 = kt * 32 + lg * 8;
        const float4* ap = (const float4*)(s + (size_t)arow * 128 + k0);
        bf16x8 af = pack_bf16x8(ap[0], ap[1]);
#pragma unroll
        for (int nt = 0; nt < 8; ++nt) {
            bf16x8 bf = *(const bf16x8*)&w1lds[(nt * 16 + lr) * 136 + k0];
            acc[nt] = __builtin_amdgcn_mfma_f32_16x16x32_bf16(af, bf, acc[nt], 0, 0, 0);
        }
    }

    const int crow = m0 + lg * 4;
#pragma unroll
    for (int nt = 0; nt < 8; ++nt) {
        int col = nt * 16 + lr;
        float bb = b1[col];
#pragma unroll
        for (int r = 0; r < 4; ++r) {
            int m = crow + r;
            if (m < N_NODES_C) {
                float x = acc[nt][r] + bb;
                x = x / (1.f + __expf(-x));
                h[(size_t)m * 128 + col] = f32_to_bf16(x);
            }
        }
    }
}

// ---------------------------------------------------------------------------
// MLP stage 2 -> pv: per nt-step, stage ONLY the needed W2t slice
// (3 chunks x 16 rows x 128 cols = 12.75KB after pad) into LDS, shared by
// all 4 waves. nt-outer triple accumulators -> each thread holds
// {phi0,phi1,phi2} for its element and writes the 16B pv record directly.
// 13KB LDS -> high occupancy; B-reads from LDS (no L2 dependence).
// ---------------------------------------------------------------------------
__global__ __launch_bounds__(256) void mlp2pv_kernel(
    const unsigned short* __restrict__ h, const unsigned short* __restrict__ W2t,
    const float* __restrict__ b2, const float* __restrict__ v,
    unsigned short* __restrict__ pv)
{
    __shared__ unsigned short wlds[3 * 16 * 136];   // 13.1 KB

    const int tid = threadIdx.x;
    const int wv = tid >> 6, lane = tid & 63;
    const int m0 = blockIdx.x * 64 + wv * 16;
    const int lr = lane & 15, lg = lane >> 4;
    int arow = m0 + lr; if (arow >= N_NODES_C) arow = N_NODES_C - 1;

    bf16x8 af2[4];
#pragma unroll
    for (int kt = 0; kt < 4; ++kt)
        af2[kt] = *(const bf16x8*)(h + (size_t)arow * 128 + kt * 32 + lg * 8);

    const int crow = m0 + lg * 4;

    for (int nt = 0; nt < 8; ++nt) {
        __syncthreads();   // previous nt's LDS reads complete
        // stage W2t slices for this nt: 768 float4 (3 per thread)
#pragma unroll
        for (int j = 0; j < 3; ++j) {
            int fi = tid + j * 256;       // 0..767
            int c    = fi >> 8;           // chunk 0..2 (256 float4 each)
            int rem  = fi & 255;
            int row  = rem >> 4;          // 0..15
            int colq = rem & 15;
            *(float4*)&wlds[(c * 16 + row) * 136 + colq * 8] =
                *(const float4*)(W2t +
                    ((size_t)(c * 128 + nt * 16 + row) * 128 + colq * 8));
        }
        __syncthreads();

        f32x4 a0 = (f32x4){0.f, 0.f, 0.f, 0.f};
        f32x4 a1 = (f32x4){0.f, 0.f, 0.f, 0.f};
        f32x4 a2 = (f32x4){0.f, 0.f, 0.f, 0.f};
#pragma unroll
        for (int kt = 0; kt < 4; ++kt) {
            const int k0 = kt * 32 + lg * 8;
            bf16x8 bf0 = *(const bf16x8*)&wlds[(      lr) * 136 + k0];
            bf16x8 bf1 = *(const bf16x8*)&wlds[(16 +  lr) * 136 + k0];
            bf16x8 bf2 = *(const bf16x8*)&wlds[(32 +  lr) * 136 + k0];
            a0 = __builtin_amdgcn_mfma_f32_16x16x32_bf16(af2[kt], bf0, a0, 0, 0, 0);
            a1 = __builtin_amdgcn_mfma_f32_16x16x32_bf16(af2[kt], bf1, a1, 0, 0, 0);
            a2 = __builtin_amdgcn_mfma_f32_16x16x32_bf16(af2[kt], bf2, a2, 0, 0, 0);
        }

        const int col = nt * 16 + lr;
        const float bb0 = b2[col], bb1 = b2[128 + col], bb2 = b2[256 + col];
#pragma unroll
        for (int r = 0; r < 4; ++r) {
            int m = crow + r;
            if (m < N_NODES_C) {
                const float* vr = v + (size_t)m * 384;
                unsigned p0 = f32_to_bf16(a0[r] + bb0);
                unsigned p1 = f32_to_bf16(a1[r] + bb1);
                unsigned p2 = f32_to_bf16(a2[r] + bb2);
                unsigned v0 = f32_to_bf16(vr[col]);
                unsigned v1 = f32_to_bf16(vr[128 + col]);
                unsigned v2 = f32_to_bf16(vr[256 + col]);
                uint4 val;
                val.x = p0 | (p1 << 16);
                val.y = p2 | (v0 << 16);
                val.z = v1 | (v2 << 16);
                val.w = 0;
                *(uint4*)((char*)pv + (size_t)m * 2048 + (size_t)col * 16) = val;
            }
        }
    }
}

// ---------------------------------------------------------------------------
// CSR build: histogram -> 3-kernel parallel scan -> fill
// ---------------------------------------------------------------------------
__global__ __launch_bounds__(256) void count_kernel(
    const int* __restrict__ dst, int* __restrict__ counts)
{
    int e = blockIdx.x * 256 + threadIdx.x;
    if (e < N_EDGES_C) atomicAdd(counts + dst[e], 1);
}

__global__ __launch_bounds__(256) void scan1_kernel(
    const int* __restrict__ counts, int* __restrict__ row_tmp,
    int* __restrict__ partial)
{
    __shared__ int sm[256];
    const int t = threadIdx.x;
    const int idx = blockIdx.x * 256 + t;
    int c = (idx < N_NODES_C) ? counts[idx] : 0;
    int x = c;
    sm[t] = x;
    __syncthreads();
#pragma unroll
    for (int off = 1; off < 256; off <<= 1) {
        int y = (t >= off) ? sm[t - off] : 0;
        __syncthreads();
        x += y;
        sm[t] = x;
        __syncthreads();
    }
    if (idx < N_NODES_C) row_tmp[idx] = x - c;
    if (t == 255) partial[blockIdx.x] = x;
}

__global__ __launch_bounds__(256) void scan2_kernel(
    const int* __restrict__ partial, int* __restrict__ poffs)
{
    __shared__ int sm[256];
    const int t = threadIdx.x;
    int c = (t < SC_BLK) ? partial[t] : 0;
    int x = c;
    sm[t] = x;
    __syncthreads();
#pragma unroll
    for (int off = 1; off < 256; off <<= 1) {
        int y = (t >= off) ? sm[t - off] : 0;
        __syncthreads();
        x += y;
        sm[t] = x;
        __syncthreads();
    }
    if (t < SC_BLK) poffs[t] = x - c;
}

__global__ __launch_bounds__(256) void scan3_kernel(
    const int* __restrict__ row_tmp, const int* __restrict__ poffs,
    int* __restrict__ row_ptr, int* __restrict__ row_fill)
{
    const int idx = blockIdx.x * 256 + threadIdx.x;
    if (idx < N_NODES_C) {
        int rp = row_tmp[idx] + poffs[blockIdx.x];
        row_ptr[idx]  = rp;
        row_fill[idx] = rp;
    }
    if (idx == 0) row_ptr[N_NODES_C] = N_EDGES_C;
}

// ---------------------------------------------------------------------------
// Edge precompute into dst-sorted slots; 64B (16-float) record per edge.
// ---------------------------------------------------------------------------
__global__ __launch_bounds__(256) void fill_kernel(
    const float* __restrict__ rel_pos, const int* __restrict__ src,
    const int* __restrict__ dst, int* __restrict__ row_fill,
    float* __restrict__ e_meta)
{
    int e = blockIdx.x * 256 + threadIdx.x;
    if (e >= N_EDGES_C) return;

    int pos = atomicAdd(row_fill + dst[e], 1);

    float x = rel_pos[3 * e + 0];
    float y = rel_pos[3 * e + 1];
    float z = rel_pos[3 * e + 2];
    float d = sqrtf(x * x + y * y + z * z);
    float invd = 1.0f / d;

    float s1 = 0.f, c1 = 0.f, fcut = 0.f, amp = 0.f;
    if (d < CUT) {
        sincosf((3.14159265358979f / CUT) * d, &s1, &c1);
        fcut = 0.5f * (c1 + 1.0f);
        amp  = invd * fcut;
    }

    float rb[NRBF];
    float sk = s1, ck = c1;
#pragma unroll
    for (int k = 0; k < NRBF; ++k) {
        rb[k] = sk * amp;
        float sn = sk * c1 + ck * s1;
        ck = ck * c1 - sk * s1;
        sk = sn;
    }

    unsigned pk[10];
#pragma unroll
    for (int kp = 0; kp < 10; ++kp)
        pk[kp] = (unsigned)f16_bits(rb[2 * kp]) | ((unsigned)f16_bits(rb[2 * kp + 1]) << 16);

    float4* mp = (float4*)(e_meta + (size_t)pos * 16);
    mp[0] = make_float4(x * invd, y * invd, z * invd, fcut);
    mp[1] = make_float4(__uint_as_float(pk[0]), __uint_as_float(pk[1]),
                        __uint_as_float(pk[2]), __uint_as_float(pk[3]));
    mp[2] = make_float4(__uint_as_float(pk[4]), __uint_as_float(pk[5]),
                        __uint_as_float(pk[6]), __uint_as_float(pk[7]));
    mp[3] = make_float4(__uint_as_float(pk[8]), __uint_as_float(pk[9]),
                        __int_as_float(src[e]), 0.f);
}

// ---------------------------------------------------------------------------
// Gather (UNCHANGED from round 12): 64B meta staged via LDS, one aligned
// dwordx4 pv gather per edge, f16-dot2 with 30 pinned packed-Wr registers.
// ---------------------------------------------------------------------------
#define COMPUTE_E(M_, U)                                                       \
    {                                                                          \
        const float4 m0 = *(const float4*)(M_);                                \
        const unsigned* mu_ = (const unsigned*)((M_) + 4);                     \
        float w0 = m0.w * br0, w1 = m0.w * br1, w2 = m0.w * br2;               \
        _Pragma("unroll")                                                      \
        for (int kp = 0; kp < 10; ++kp) {                                      \
            f16x2 rh = u2h2(mu_[kp]);                                          \
            w0 = __builtin_amdgcn_fdot2(rh, u2h2(wrp0[kp]), w0, false);        \
            w1 = __builtin_amdgcn_fdot2(rh, u2h2(wrp1[kp]), w1, false);        \
            w2 = __builtin_amdgcn_fdot2(rh, u2h2(wrp2[kp]), w2, false);        \
        }                                                                      \
        float P0 = bf16_to_f32((unsigned short)((U).x & 0xFFFFu));             \
        float P1 = bf16_to_f32((unsigned short)((U).x >> 16));                 \
        float P2 = bf16_to_f32((unsigned short)((U).y & 0xFFFFu));             \
        float V0 = bf16_to_f32((unsigned short)((U).y >> 16));                 \
        float V1 = bf16_to_f32((unsigned short)((U).z & 0xFFFFu));             \
        float V2 = bf16_to_f32((unsigned short)((U).z >> 16));                 \
        float sv = w0 * P0;                                                    \
        float ss = w1 * P1;                                                    \
        float sr = w2 * P2;                                                    \
        acc_s  += ss;                                                          \
        acc_v0 += V0 * sv + m0.x * sr;                                         \
        acc_v1 += V1 * sv + m0.y * sr;                                         \
        acc_v2 += V2 * sv + m0.z * sr;                                         \
    }

#define LOADPV(U, SI)                                                          \
    U = *(const uint4*)((const char*)pv + (size_t)(SI) * 2048 + (size_t)f * 16);

#define STORE_NODE(N_, AS, A0, A1, A2)                                         \
    {                                                                          \
        out_s[(size_t)(N_) * 128 + f] = AS;                                    \
        out_v[(size_t)(N_) * 384 +       f] = A0;                              \
        out_v[(size_t)(N_) * 384 + 128 + f] = A1;                              \
        out_v[(size_t)(N_) * 384 + 256 + f] = A2;                              \
    }

#define BOUNDARY(GE)                                                           \
    if ((GE) + 1 == end_cur) {                                                 \
        STORE_NODE(cur, acc_s, acc_v0, acc_v1, acc_v2);                        \
        acc_s = acc_v0 = acc_v1 = acc_v2 = 0.f;                                \
        ++cur;                                                                 \
        while (cur < nhi) {                                                    \
            int ne_ = row_ptr[cur + 1];                                        \
            if (ne_ != (GE) + 1) { end_cur = ne_; break; }                     \
            STORE_NODE(cur, 0.f, 0.f, 0.f, 0.f);                               \
            ++cur;                                                             \
        }                                                                      \
    }

__global__ __launch_bounds__(128) void gather_packed_kernel(
    const unsigned short* __restrict__ pv, const unsigned* __restrict__ wrh,
    const float* __restrict__ br, const int* __restrict__ row_ptr,
    const float* __restrict__ e_meta,
    float* __restrict__ out_v, float* __restrict__ out_s)
{
    __shared__ float meta_lds[2][BATCH * 16];

    const int f = threadIdx.x;               // 0..127 feature lane
    const int gid = blockIdx.x;
    const int chunk = (N_NODES_C + GBLOCKS - 1) / GBLOCKS;
    const int nlo = gid * chunk;
    if (nlo >= N_NODES_C) return;
    const int nhi = min(nlo + chunk, N_NODES_C);

    // per-lane Wr f16-pairs -> 30 registers, pinned against remat
    unsigned wrp0[10], wrp1[10], wrp2[10];
    {
        const unsigned* wp = wrh + (size_t)f * 30;
#pragma unroll
        for (int i = 0; i < 10; ++i) {
            wrp0[i] = wp[i];
            wrp1[i] = wp[10 + i];
            wrp2[i] = wp[20 + i];
        }
#pragma unroll
        for (int i = 0; i < 10; ++i)
            asm volatile("" : "+v"(wrp0[i]), "+v"(wrp1[i]), "+v"(wrp2[i]));
    }
    const float br0 = br[f], br1 = br[128 + f], br2 = br[256 + f];

    const int gbeg = row_ptr[nlo];
    const int gend = row_ptr[nhi];
    const int nedge = gend - gbeg;

    float acc_s = 0.f, acc_v0 = 0.f, acc_v1 = 0.f, acc_v2 = 0.f;

    int cur = nlo;
    while (cur < nhi && row_ptr[cur + 1] == gbeg) {
        STORE_NODE(cur, 0.f, 0.f, 0.f, 0.f);
        ++cur;
    }
    int end_cur = (cur < nhi) ? row_ptr[cur + 1] : gbeg;

    // stage batch 0: 32 records x 64B = 128 float4 (one per thread)
    if (nedge > 0) {
        const float4* src0 = (const float4*)(e_meta + (size_t)gbeg * 16);
        ((float4*)meta_lds[0])[threadIdx.x] = src0[threadIdx.x];
    }
    __syncthreads();

    const int total_batches = (nedge + BATCH - 1) / BATCH;
    for (int b = 0; b < total_batches; ++b) {
        const int bstart = b * BATCH;
        const int bcount = min(BATCH, nedge - bstart);
        const bool have_next = (b + 1 < total_batches);

        float4 st;
        if (have_next)
            st = ((const float4*)(e_meta + (size_t)(gbeg + bstart + BATCH) * 16))[threadIdx.x];

        const float* Mb = meta_lds[b & 1];

        uint4 uA, uB;
        {
            int si = ((const int*)Mb)[14];
            LOADPV(uA, si);
        }

        int t = 0;
        while (t < bcount) {
            if (t + 1 < bcount) {
                int si = ((const int*)(Mb + (t + 1) * 16))[14];
                LOADPV(uB, si);
            }
            COMPUTE_E(Mb + t * 16, uA);
            BOUNDARY(gbeg + bstart + t);
            ++t; if (t >= bcount) break;

            if (t + 1 < bcount) {
                int si = ((const int*)(Mb + (t + 1) * 16))[14];
                LOADPV(uA, si);
            }
            COMPUTE_E(Mb + t * 16, uB);
            BOUNDARY(gbeg + bstart + t);
            ++t;
        }

        if (have_next) ((float4*)meta_lds[(b + 1) & 1])[threadIdx.x] = st;
        __syncthreads();
    }
}

// ---------------------------------------------------------------------------
extern "C" void kernel_launch(void* const* d_in, const int* in_sizes, int n_in,
                              void* d_out, int out_size, void* d_ws, size_t ws_size,
                              hipStream_t stream)
{
    const float* s  = (const float*)d_in[0];
    const float* v  = (const float*)d_in[1];
    const float* rp = (const float*)d_in[2];
    const float* W1 = (const float*)d_in[3];
    const float* b1 = (const float*)d_in[4];
    const float* W2 = (const float*)d_in[5];
    const float* b2 = (const float*)d_in[6];
    const float* Wr = (const float*)d_in[7];
    const float* br = (const float*)d_in[8];
    const int* src  = (const int*)d_in[9];
    const int* dst  = (const int*)d_in[10];

    float* out   = (float*)d_out;
    float* out_v = out;                                    // 50000*3*128
    float* out_s = out + (size_t)N_NODES_C * 3 * FDIM;     // 50000*128

    // workspace layout (~130 MB total)
    char* ws = (char*)d_ws;
    float* e_meta = (float*)ws;                 ws += ((size_t)N_EDGES_C * 16 + 256) * sizeof(float);
    unsigned short* W1t = (unsigned short*)ws;  ws += (size_t)128 * 128 * sizeof(unsigned short);
    unsigned short* W2t = (unsigned short*)ws;  ws += (size_t)384 * 128 * sizeof(unsigned short);
    unsigned* wrh = (unsigned*)ws;              ws += (size_t)128 * 30 * sizeof(unsigned);
    int* counts   = (int*)ws;                   ws += (size_t)N_NODES_C * sizeof(int);
    int* row_ptr  = (int*)ws;                   ws += (size_t)(N_NODES_C + 4) * sizeof(int);
    int* row_fill = (int*)ws;                   ws += (size_t)N_NODES_C * sizeof(int);
    int* row_tmp  = (int*)ws;                   ws += (size_t)N_NODES_C * sizeof(int);
    int* partial  = (int*)ws;                   ws += (size_t)256 * sizeof(int);
    int* poffs    = (int*)ws;                   ws += (size_t)256 * sizeof(int);
    unsigned short* h = (unsigned short*)ws;    ws += (size_t)N_NODES_C * 128 * sizeof(unsigned short);
    unsigned short* pv = (unsigned short*)ws;   // 50000 * 2048B = 102.4 MB

    hipMemsetAsync(counts, 0, (size_t)N_NODES_C * sizeof(int), stream);

    count_kernel<<<(N_EDGES_C + 255) / 256, 256, 0, stream>>>(dst, counts);
    scan1_kernel<<<SC_BLK, 256, 0, stream>>>(counts, row_tmp, partial);
    scan2_kernel<<<1, 256, 0, stream>>>(partial, poffs);
    scan3_kernel<<<SC_BLK, 256, 0, stream>>>(row_tmp, poffs, row_ptr, row_fill);
    fill_kernel<<<(N_EDGES_C + 255) / 256, 256, 0, stream>>>(rp, src, dst, row_fill, e_meta);

    prep_w_kernel<<<256, 256, 0, stream>>>(W1, W2, W1t, W2t);
    prep_wr_kernel<<<15, 256, 0, stream>>>(Wr, wrh);
    mlp1w_kernel<<<(N_NODES_C + 63) / 64, 256, 0, stream>>>(s, W1t, b1, h);
    mlp2pv_kernel<<<(N_NODES_C + 63) / 64, 256, 0, stream>>>(h, W2t, b2, v, pv);

    gather_packed_kernel<<<GBLOCKS, 128, 0, stream>>>(pv, wrh, br, row_ptr,
                                                      e_meta, out_v, out_s);
}

// Round 15
// 205.311 us; speedup vs baseline: 1.5059x; 1.1143x over previous
//
#include <hip/hip_runtime.h>
#include <math.h>

#define N_NODES_C 50000
#define N_EDGES_C 200000
#define FDIM 128
#define NRBF 20
#define CUT 5.0f
#define SC_BLK 196   // ceil(50000/256)
#define GBLOCKS 6250 // 8 nodes per block
#define BATCH 32     // edges staged per LDS batch (32 x 64B = 2KB = 128 float4)

typedef short  bf16x8 __attribute__((ext_vector_type(8)));
typedef float  f32x4  __attribute__((ext_vector_type(4)));
typedef unsigned int u32x3 __attribute__((ext_vector_type(3)));
typedef _Float16 f16x2 __attribute__((ext_vector_type(2)));

__device__ __forceinline__ unsigned short f32_to_bf16(float f) {
    unsigned u = __float_as_uint(f);
    unsigned r = (u + 0x7FFFu + ((u >> 16) & 1u)) >> 16;   // RNE
    return (unsigned short)r;
}
__device__ __forceinline__ float bf16_to_f32(unsigned short h) {
    return __uint_as_float(((unsigned)h) << 16);
}
__device__ __forceinline__ unsigned short f16_bits(float x) {
    _Float16 h = (_Float16)x;
    unsigned short b;
    __builtin_memcpy(&b, &h, 2);
    return b;
}
__device__ __forceinline__ f16x2 u2h2(unsigned u) {
    f16x2 r;
    __builtin_memcpy(&r, &u, 4);
    return r;
}
__device__ __forceinline__ bf16x8 pack_bf16x8(float4 a, float4 b) {
    bf16x8 r;
    r[0] = (short)f32_to_bf16(a.x); r[1] = (short)f32_to_bf16(a.y);
    r[2] = (short)f32_to_bf16(a.z); r[3] = (short)f32_to_bf16(a.w);
    r[4] = (short)f32_to_bf16(b.x); r[5] = (short)f32_to_bf16(b.y);
    r[6] = (short)f32_to_bf16(b.z); r[7] = (short)f32_to_bf16(b.w);
    return r;
}

// ---------------------------------------------------------------------------
// Weight prep: W1t[n][k] = bf16(W1[k][n]) (128x128), W2t[n][k] = bf16(W2[k][n])
// ---------------------------------------------------------------------------
__global__ __launch_bounds__(256) void prep_w_kernel(
    const float* __restrict__ W1, const float* __restrict__ W2,
    unsigned short* __restrict__ W1t, unsigned short* __restrict__ W2t)
{
    int i = blockIdx.x * 256 + threadIdx.x;
    if (i < 128 * 128) {
        int n = i >> 7, k = i & 127;
        W1t[i] = f32_to_bf16(W1[k * 128 + n]);
    }
    int j = i - 128 * 128;
    if (j >= 0 && j < 384 * 128) {
        int n = j >> 7, k = j & 127;
        W2t[j] = f32_to_bf16(W2[k * 384 + n]);
    }
}

// ---------------------------------------------------------------------------
// Wr prep: per-lane packed f16 pairs.
// ---------------------------------------------------------------------------
__global__ __launch_bounds__(256) void prep_wr_kernel(
    const float* __restrict__ Wr, unsigned* __restrict__ wrh)
{
    int idx = blockIdx.x * 256 + threadIdx.x;
    if (idx >= 128 * 30) return;
    int f  = idx / 30;
    int r  = idx % 30;
    int sec = r / 10, kp = r % 10;
    int col = sec * 128 + f;
    unsigned lo = f16_bits(Wr[(2 * kp)     * 384 + col]);
    unsigned hi = f16_bits(Wr[(2 * kp + 1) * 384 + col]);
    wrh[idx] = lo | (hi << 16);
}

// ---------------------------------------------------------------------------
// MLP stage 1: h = silu(s @ W1 + b1). W1t staged in LDS once per block
// (round-13 lesson: streaming traffic evicts weights from L2; LDS B-reads
// are eviction-immune). Row stride padded to 136 ushorts.
// ---------------------------------------------------------------------------
__global__ __launch_bounds__(256) void mlp1w_kernel(
    const float* __restrict__ s, const unsigned short* __restrict__ W1t,
    const float* __restrict__ b1, unsigned short* __restrict__ h)
{
    __shared__ unsigned short w1lds[128 * 136];   // 34.8 KB

    const int tid = threadIdx.x;
#pragma unroll
    for (int j = 0; j < 8; ++j) {
        int fi = tid + j * 256;           // float4 index 0..2047
        int row  = fi >> 4;
        int colq = fi & 15;
        *(float4*)&w1lds[row * 136 + colq * 8] =
            *(const float4*)(W1t + (size_t)fi * 8);
    }
    __syncthreads();

    const int wv = tid >> 6, lane = tid & 63;
    const int m0 = blockIdx.x * 64 + wv * 16;
    const int lr = lane & 15, lg = lane >> 4;
    int arow = m0 + lr; if (arow >= N_NODES_C) arow = N_NODES_C - 1;

    f32x4 acc[8];
#pragma unroll
    for (int nt = 0; nt < 8; ++nt) acc[nt] = (f32x4){0.f, 0.f, 0.f, 0.f};

#pragma unroll
    for (int kt = 0; kt < 4; ++kt) {
        const int k0 = kt * 32 + lg * 8;
        const float4* ap = (const float4*)(s + (size_t)arow * 128 + k0);
        bf16x8 af = pack_bf16x8(ap[0], ap[1]);
#pragma unroll
        for (int nt = 0; nt < 8; ++nt) {
            bf16x8 bf = *(const bf16x8*)&w1lds[(nt * 16 + lr) * 136 + k0];
            acc[nt] = __builtin_amdgcn_mfma_f32_16x16x32_bf16(af, bf, acc[nt], 0, 0, 0);
        }
    }

    const int crow = m0 + lg * 4;
#pragma unroll
    for (int nt = 0; nt < 8; ++nt) {
        int col = nt * 16 + lr;
        float bb = b1[col];
#pragma unroll
        for (int r = 0; r < 4; ++r) {
            int m = crow + r;
            if (m < N_NODES_C) {
                float x = acc[nt][r] + bb;
                x = x / (1.f + __expf(-x));
                h[(size_t)m * 128 + col] = f32_to_bf16(x);
            }
        }
    }
}

// ---------------------------------------------------------------------------
// MLP stage 2 -> pv: per nt-step, the needed W2t slice (12.75KB) in LDS,
// DOUBLE-BUFFERED (round-14 lesson: single-buffer had 8 serial stage stalls
// of ~700cy each; now next-slice loads issue before compute, ds_write after,
// one barrier per nt). pv records are 12B (un-padded, 76.8MB surface).
// ---------------------------------------------------------------------------
__global__ __launch_bounds__(256) void mlp2pv_kernel(
    const unsigned short* __restrict__ h, const unsigned short* __restrict__ W2t,
    const float* __restrict__ b2, const float* __restrict__ v,
    unsigned short* __restrict__ pv)
{
    __shared__ unsigned short wlds[2][3 * 16 * 136];   // 26.2 KB

    const int tid = threadIdx.x;
    const int wv = tid >> 6, lane = tid & 63;
    const int m0 = blockIdx.x * 64 + wv * 16;
    const int lr = lane & 15, lg = lane >> 4;
    int arow = m0 + lr; if (arow >= N_NODES_C) arow = N_NODES_C - 1;

    bf16x8 af2[4];
#pragma unroll
    for (int kt = 0; kt < 4; ++kt)
        af2[kt] = *(const bf16x8*)(h + (size_t)arow * 128 + kt * 32 + lg * 8);

    // staging addresses for this thread (3 float4 per nt)
    const int fi0 = tid, fi1 = tid + 256, fi2 = tid + 512;
#define SLICE_SRC(FI, NT)                                                      \
    (const float4*)(W2t + ((size_t)(((FI) >> 8) * 128 + (NT) * 16 +            \
                            (((FI) & 255) >> 4)) * 128 + ((FI) & 15) * 8))
#define SLICE_DST(BUF, FI)                                                     \
    (float4*)&wlds[BUF][(((FI) >> 8) * 16 + (((FI) & 255) >> 4)) * 136 +       \
                        ((FI) & 15) * 8]

    // prologue: stage nt=0 into buf 0
    {
        float4 r0 = *SLICE_SRC(fi0, 0);
        float4 r1 = *SLICE_SRC(fi1, 0);
        float4 r2 = *SLICE_SRC(fi2, 0);
        *SLICE_DST(0, fi0) = r0;
        *SLICE_DST(0, fi1) = r1;
        *SLICE_DST(0, fi2) = r2;
    }
    __syncthreads();

    const int crow = m0 + lg * 4;

    for (int nt = 0; nt < 8; ++nt) {
        float4 r0, r1, r2;
        if (nt + 1 < 8) {               // issue next-slice loads early
            r0 = *SLICE_SRC(fi0, nt + 1);
            r1 = *SLICE_SRC(fi1, nt + 1);
            r2 = *SLICE_SRC(fi2, nt + 1);
        }

        const unsigned short* W = wlds[nt & 1];
        f32x4 a0 = (f32x4){0.f, 0.f, 0.f, 0.f};
        f32x4 a1 = (f32x4){0.f, 0.f, 0.f, 0.f};
        f32x4 a2 = (f32x4){0.f, 0.f, 0.f, 0.f};
#pragma unroll
        for (int kt = 0; kt < 4; ++kt) {
            const int k0 = kt * 32 + lg * 8;
            bf16x8 bf0 = *(const bf16x8*)&W[(      lr) * 136 + k0];
            bf16x8 bf1 = *(const bf16x8*)&W[(16 +  lr) * 136 + k0];
            bf16x8 bf2 = *(const bf16x8*)&W[(32 +  lr) * 136 + k0];
            a0 = __builtin_amdgcn_mfma_f32_16x16x32_bf16(af2[kt], bf0, a0, 0, 0, 0);
            a1 = __builtin_amdgcn_mfma_f32_16x16x32_bf16(af2[kt], bf1, a1, 0, 0, 0);
            a2 = __builtin_amdgcn_mfma_f32_16x16x32_bf16(af2[kt], bf2, a2, 0, 0, 0);
        }

        const int col = nt * 16 + lr;
        const float bb0 = b2[col], bb1 = b2[128 + col], bb2 = b2[256 + col];
#pragma unroll
        for (int r = 0; r < 4; ++r) {
            int m = crow + r;
            if (m < N_NODES_C) {
                const float* vr = v + (size_t)m * 384;
                unsigned p0 = f32_to_bf16(a0[r] + bb0);
                unsigned p1 = f32_to_bf16(a1[r] + bb1);
                unsigned p2 = f32_to_bf16(a2[r] + bb2);
                unsigned v0 = f32_to_bf16(vr[col]);
                unsigned v1 = f32_to_bf16(vr[128 + col]);
                unsigned v2 = f32_to_bf16(vr[256 + col]);
                u32x3 val;
                val.x = p0 | (p1 << 16);
                val.y = p2 | (v0 << 16);
                val.z = v1 | (v2 << 16);
                *(u32x3*)((char*)pv + (size_t)m * 1536 + (size_t)col * 12) = val;
            }
        }

        if (nt + 1 < 8) {               // write next slice to the other buffer
            *SLICE_DST((nt + 1) & 1, fi0) = r0;
            *SLICE_DST((nt + 1) & 1, fi1) = r1;
            *SLICE_DST((nt + 1) & 1, fi2) = r2;
        }
        __syncthreads();
    }
#undef SLICE_SRC
#undef SLICE_DST
}

// ---------------------------------------------------------------------------
// CSR build: histogram -> 3-kernel parallel scan -> fill
// ---------------------------------------------------------------------------
__global__ __launch_bounds__(256) void count_kernel(
    const int* __restrict__ dst, int* __restrict__ counts)
{
    int e = blockIdx.x * 256 + threadIdx.x;
    if (e < N_EDGES_C) atomicAdd(counts + dst[e], 1);
}

__global__ __launch_bounds__(256) void scan1_kernel(
    const int* __restrict__ counts, int* __restrict__ row_tmp,
    int* __restrict__ partial)
{
    __shared__ int sm[256];
    const int t = threadIdx.x;
    const int idx = blockIdx.x * 256 + t;
    int c = (idx < N_NODES_C) ? counts[idx] : 0;
    int x = c;
    sm[t] = x;
    __syncthreads();
#pragma unroll
    for (int off = 1; off < 256; off <<= 1) {
        int y = (t >= off) ? sm[t - off] : 0;
        __syncthreads();
        x += y;
        sm[t] = x;
        __syncthreads();
    }
    if (idx < N_NODES_C) row_tmp[idx] = x - c;
    if (t == 255) partial[blockIdx.x] = x;
}

__global__ __launch_bounds__(256) void scan2_kernel(
    const int* __restrict__ partial, int* __restrict__ poffs)
{
    __shared__ int sm[256];
    const int t = threadIdx.x;
    int c = (t < SC_BLK) ? partial[t] : 0;
    int x = c;
    sm[t] = x;
    __syncthreads();
#pragma unroll
    for (int off = 1; off < 256; off <<= 1) {
        int y = (t >= off) ? sm[t - off] : 0;
        __syncthreads();
        x += y;
        sm[t] = x;
        __syncthreads();
    }
    if (t < SC_BLK) poffs[t] = x - c;
}

__global__ __launch_bounds__(256) void scan3_kernel(
    const int* __restrict__ row_tmp, const int* __restrict__ poffs,
    int* __restrict__ row_ptr, int* __restrict__ row_fill)
{
    const int idx = blockIdx.x * 256 + threadIdx.x;
    if (idx < N_NODES_C) {
        int rp = row_tmp[idx] + poffs[blockIdx.x];
        row_ptr[idx]  = rp;
        row_fill[idx] = rp;
    }
    if (idx == 0) row_ptr[N_NODES_C] = N_EDGES_C;
}

// ---------------------------------------------------------------------------
// Edge precompute into dst-sorted slots; 64B (16-float) record per edge.
// ---------------------------------------------------------------------------
__global__ __launch_bounds__(256) void fill_kernel(
    const float* __restrict__ rel_pos, const int* __restrict__ src,
    const int* __restrict__ dst, int* __restrict__ row_fill,
    float* __restrict__ e_meta)
{
    int e = blockIdx.x * 256 + threadIdx.x;
    if (e >= N_EDGES_C) return;

    int pos = atomicAdd(row_fill + dst[e], 1);

    float x = rel_pos[3 * e + 0];
    float y = rel_pos[3 * e + 1];
    float z = rel_pos[3 * e + 2];
    float d = sqrtf(x * x + y * y + z * z);
    float invd = 1.0f / d;

    float s1 = 0.f, c1 = 0.f, fcut = 0.f, amp = 0.f;
    if (d < CUT) {
        sincosf((3.14159265358979f / CUT) * d, &s1, &c1);
        fcut = 0.5f * (c1 + 1.0f);
        amp  = invd * fcut;
    }

    float rb[NRBF];
    float sk = s1, ck = c1;
#pragma unroll
    for (int k = 0; k < NRBF; ++k) {
        rb[k] = sk * amp;
        float sn = sk * c1 + ck * s1;
        ck = ck * c1 - sk * s1;
        sk = sn;
    }

    unsigned pk[10];
#pragma unroll
    for (int kp = 0; kp < 10; ++kp)
        pk[kp] = (unsigned)f16_bits(rb[2 * kp]) | ((unsigned)f16_bits(rb[2 * kp + 1]) << 16);

    float4* mp = (float4*)(e_meta + (size_t)pos * 16);
    mp[0] = make_float4(x * invd, y * invd, z * invd, fcut);
    mp[1] = make_float4(__uint_as_float(pk[0]), __uint_as_float(pk[1]),
                        __uint_as_float(pk[2]), __uint_as_float(pk[3]));
    mp[2] = make_float4(__uint_as_float(pk[4]), __uint_as_float(pk[5]),
                        __uint_as_float(pk[6]), __uint_as_float(pk[7]));
    mp[3] = make_float4(__uint_as_float(pk[8]), __uint_as_float(pk[9]),
                        __int_as_float(src[e]), 0.f);
}

// ---------------------------------------------------------------------------
// Gather: 64B meta staged via LDS, one 12B pv gather (dwordx3) per edge,
// f16-dot2 for the Wr dot (wrh is L1-resident; remat is cheap at 40 VGPR).
// ---------------------------------------------------------------------------
#define COMPUTE_E(M_, U)                                                       \
    {                                                                          \
        const float4 m0 = *(const float4*)(M_);                                \
        const unsigned* mu_ = (const unsigned*)((M_) + 4);                     \
        float w0 = m0.w * br0, w1 = m0.w * br1, w2 = m0.w * br2;               \
        _Pragma("unroll")                                                      \
        for (int kp = 0; kp < 10; ++kp) {                                      \
            f16x2 rh = u2h2(mu_[kp]);                                          \
            w0 = __builtin_amdgcn_fdot2(rh, u2h2(wrp0[kp]), w0, false);        \
            w1 = __builtin_amdgcn_fdot2(rh, u2h2(wrp1[kp]), w1, false);        \
            w2 = __builtin_amdgcn_fdot2(rh, u2h2(wrp2[kp]), w2, false);        \
        }                                                                      \
        float P0 = bf16_to_f32((unsigned short)((U).x & 0xFFFFu));             \
        float P1 = bf16_to_f32((unsigned short)((U).x >> 16));                 \
        float P2 = bf16_to_f32((unsigned short)((U).y & 0xFFFFu));             \
        float V0 = bf16_to_f32((unsigned short)((U).y >> 16));                 \
        float V1 = bf16_to_f32((unsigned short)((U).z & 0xFFFFu));             \
        float V2 = bf16_to_f32((unsigned short)((U).z >> 16));                 \
        float sv = w0 * P0;                                                    \
        float ss = w1 * P1;                                                    \
        float sr = w2 * P2;                                                    \
        acc_s  += ss;                                                          \
        acc_v0 += V0 * sv + m0.x * sr;                                         \
        acc_v1 += V1 * sv + m0.y * sr;                                         \
        acc_v2 += V2 * sv + m0.z * sr;                                         \
    }

#define LOADPV(U, SI)                                                          \
    U = *(const u32x3*)((const char*)pv + (size_t)(SI) * 1536 + (size_t)f * 12);

#define STORE_NODE(N_, AS, A0, A1, A2)                                         \
    {                                                                          \
        out_s[(size_t)(N_) * 128 + f] = AS;                                    \
        out_v[(size_t)(N_) * 384 +       f] = A0;                              \
        out_v[(size_t)(N_) * 384 + 128 + f] = A1;                              \
        out_v[(size_t)(N_) * 384 + 256 + f] = A2;                              \
    }

#define BOUNDARY(GE)                                                           \
    if ((GE) + 1 == end_cur) {                                                 \
        STORE_NODE(cur, acc_s, acc_v0, acc_v1, acc_v2);                        \
        acc_s = acc_v0 = acc_v1 = acc_v2 = 0.f;                                \
        ++cur;                                                                 \
        while (cur < nhi) {                                                    \
            int ne_ = row_ptr[cur + 1];                                        \
            if (ne_ != (GE) + 1) { end_cur = ne_; break; }                     \
            STORE_NODE(cur, 0.f, 0.f, 0.f, 0.f);                               \
            ++cur;                                                             \
        }                                                                      \
    }

__global__ __launch_bounds__(128) void gather_packed_kernel(
    const unsigned short* __restrict__ pv, const unsigned* __restrict__ wrh,
    const float* __restrict__ br, const int* __restrict__ row_ptr,
    const float* __restrict__ e_meta,
    float* __restrict__ out_v, float* __restrict__ out_s)
{
    __shared__ float meta_lds[2][BATCH * 16];

    const int f = threadIdx.x;               // 0..127 feature lane
    const int gid = blockIdx.x;
    const int chunk = (N_NODES_C + GBLOCKS - 1) / GBLOCKS;   // 8
    const int nlo = gid * chunk;
    if (nlo >= N_NODES_C) return;
    const int nhi = min(nlo + chunk, N_NODES_C);

    unsigned wrp0[10], wrp1[10], wrp2[10];
    {
        const unsigned* wp = wrh + (size_t)f * 30;
#pragma unroll
        for (int i = 0; i < 10; ++i) {
            wrp0[i] = wp[i];
            wrp1[i] = wp[10 + i];
            wrp2[i] = wp[20 + i];
        }
#pragma unroll
        for (int i = 0; i < 10; ++i)
            asm volatile("" : "+v"(wrp0[i]), "+v"(wrp1[i]), "+v"(wrp2[i]));
    }
    const float br0 = br[f], br1 = br[128 + f], br2 = br[256 + f];

    const int gbeg = row_ptr[nlo];
    const int gend = row_ptr[nhi];
    const int nedge = gend - gbeg;

    float acc_s = 0.f, acc_v0 = 0.f, acc_v1 = 0.f, acc_v2 = 0.f;

    int cur = nlo;
    while (cur < nhi && row_ptr[cur + 1] == gbeg) {
        STORE_NODE(cur, 0.f, 0.f, 0.f, 0.f);
        ++cur;
    }
    int end_cur = (cur < nhi) ? row_ptr[cur + 1] : gbeg;

    // stage batch 0: 32 records x 64B = 128 float4 (one per thread)
    if (nedge > 0) {
        const float4* src0 = (const float4*)(e_meta + (size_t)gbeg * 16);
        ((float4*)meta_lds[0])[threadIdx.x] = src0[threadIdx.x];
    }
    __syncthreads();

    const int total_batches = (nedge + BATCH - 1) / BATCH;
    for (int b = 0; b < total_batches; ++b) {
        const int bstart = b * BATCH;
        const int bcount = min(BATCH, nedge - bstart);
        const bool have_next = (b + 1 < total_batches);

        float4 st;
        if (have_next)
            st = ((const float4*)(e_meta + (size_t)(gbeg + bstart + BATCH) * 16))[threadIdx.x];

        const float* Mb = meta_lds[b & 1];

        u32x3 uA, uB;
        {
            int si = ((const int*)Mb)[14];
            LOADPV(uA, si);
        }

        int t = 0;
        while (t < bcount) {
            if (t + 1 < bcount) {
                int si = ((const int*)(Mb + (t + 1) * 16))[14];
                LOADPV(uB, si);
            }
            COMPUTE_E(Mb + t * 16, uA);
            BOUNDARY(gbeg + bstart + t);
            ++t; if (t >= bcount) break;

            if (t + 1 < bcount) {
                int si = ((const int*)(Mb + (t + 1) * 16))[14];
                LOADPV(uA, si);
            }
            COMPUTE_E(Mb + t * 16, uB);
            BOUNDARY(gbeg + bstart + t);
            ++t;
        }

        if (have_next) ((float4*)meta_lds[(b + 1) & 1])[threadIdx.x] = st;
        __syncthreads();
    }
}

// ---------------------------------------------------------------------------
extern "C" void kernel_launch(void* const* d_in, const int* in_sizes, int n_in,
                              void* d_out, int out_size, void* d_ws, size_t ws_size,
                              hipStream_t stream)
{
    const float* s  = (const float*)d_in[0];
    const float* v  = (const float*)d_in[1];
    const float* rp = (const float*)d_in[2];
    const float* W1 = (const float*)d_in[3];
    const float* b1 = (const float*)d_in[4];
    const float* W2 = (const float*)d_in[5];
    const float* b2 = (const float*)d_in[6];
    const float* Wr = (const float*)d_in[7];
    const float* br = (const float*)d_in[8];
    const int* src  = (const int*)d_in[9];
    const int* dst  = (const int*)d_in[10];

    float* out   = (float*)d_out;
    float* out_v = out;                                    // 50000*3*128
    float* out_s = out + (size_t)N_NODES_C * 3 * FDIM;     // 50000*128

    // workspace layout (~105 MB total)
    char* ws = (char*)d_ws;
    float* e_meta = (float*)ws;                 ws += ((size_t)N_EDGES_C * 16 + 256) * sizeof(float);
    unsigned short* W1t = (unsigned short*)ws;  ws += (size_t)128 * 128 * sizeof(unsigned short);
    unsigned short* W2t = (unsigned short*)ws;  ws += (size_t)384 * 128 * sizeof(unsigned short);
    unsigned* wrh = (unsigned*)ws;              ws += (size_t)128 * 30 * sizeof(unsigned);
    int* counts   = (int*)ws;                   ws += (size_t)N_NODES_C * sizeof(int);
    int* row_ptr  = (int*)ws;                   ws += (size_t)(N_NODES_C + 4) * sizeof(int);
    int* row_fill = (int*)ws;                   ws += (size_t)N_NODES_C * sizeof(int);
    int* row_tmp  = (int*)ws;                   ws += (size_t)N_NODES_C * sizeof(int);
    int* partial  = (int*)ws;                   ws += (size_t)256 * sizeof(int);
    int* poffs    = (int*)ws;                   ws += (size_t)256 * sizeof(int);
    unsigned short* h = (unsigned short*)ws;    ws += (size_t)N_NODES_C * 128 * sizeof(unsigned short);
    unsigned short* pv = (unsigned short*)ws;   // 50000 * 1536B = 76.8 MB

    hipMemsetAsync(counts, 0, (size_t)N_NODES_C * sizeof(int), stream);

    count_kernel<<<(N_EDGES_C + 255) / 256, 256, 0, stream>>>(dst, counts);
    scan1_kernel<<<SC_BLK, 256, 0, stream>>>(counts, row_tmp, partial);
    scan2_kernel<<<1, 256, 0, stream>>>(partial, poffs);
    scan3_kernel<<<SC_BLK, 256, 0, stream>>>(row_tmp, poffs, row_ptr, row_fill);
    fill_kernel<<<(N_EDGES_C + 255) / 256, 256, 0, stream>>>(rp, src, dst, row_fill, e_meta);

    prep_w_kernel<<<256, 256, 0, stream>>>(W1, W2, W1t, W2t);
    prep_wr_kernel<<<15, 256, 0, stream>>>(Wr, wrh);
    mlp1w_kernel<<<(N_NODES_C + 63) / 64, 256, 0, stream>>>(s, W1t, b1, h);
    mlp2pv_kernel<<<(N_NODES_C + 63) / 64, 256, 0, stream>>>(h, W2t, b2, v, pv);

    gather_packed_kernel<<<GBLOCKS, 128, 0, stream>>>(pv, wrh, br, row_ptr,
                                                      e_meta, out_v, out_s);
}